// Round 3
// baseline (2903.514 us; speedup 1.0000x reference)
//
#include <hip/hip_runtime.h>

// GCN: h1 = relu(gcnconv(x,W1,b1)); h2 = relu(gcnconv(h1,W2,b2));
// out = sigmoid(mean(h2,0) @ Wf + bf)
// Factorization: hp = (x@W)*dinv[row];  out[d] = dinv[d]*(sum_{e:dst=d} hp[src] + hp[d]) + b
// Edges are bucket-partitioned by dst>>7; aggregation accumulates in a
// 128x64 f32 LDS tile per bucket (no global f32 atomics, no per-dst CSR).

typedef unsigned long long u64;
typedef unsigned short u16;

constexpr int HID  = 64;
constexpr int SH   = 7;          // bucket shift
constexpr int BK   = 128;        // nodes per bucket
constexpr int BPAD = 1024;       // padded bucket count (scan width)
constexpr int CH   = 8192;       // edges per partition block

static __device__ __forceinline__ float bf2f(u16 v) {
    return __uint_as_float(((unsigned int)v) << 16);
}
static __device__ __forceinline__ u16 f2bf(float f) {
    unsigned int u = __float_as_uint(f);
    return (u16)((u + 0x7FFFu + ((u >> 16) & 1u)) >> 16);
}

// ---------- bucket histogram (LDS-privatized) ----------
__global__ __launch_bounds__(256) void hist_kernel(const int* __restrict__ dst,
                                                   int* __restrict__ bcnt, int ne, int B) {
    __shared__ int h[BPAD];
    for (int i = threadIdx.x; i < BPAD; i += 256) h[i] = 0;
    __syncthreads();
    int i = blockIdx.x * 256 + threadIdx.x, st = gridDim.x * 256;
    for (; i < ne; i += st) atomicAdd(&h[dst[i] >> SH], 1);
    __syncthreads();
    for (int b = threadIdx.x; b < B; b += 256) if (h[b]) atomicAdd(&bcnt[b], h[b]);
}

// ---------- exclusive scan of bucket counts (single block) ----------
__global__ __launch_bounds__(256) void bucket_scan_kernel(const int* __restrict__ bcnt,
                                                          int* __restrict__ boff,
                                                          int* __restrict__ bcur, int B) {
    __shared__ int ssc[256];
    int t = threadIdx.x, base = t * 4;
    int c[4];
    #pragma unroll
    for (int j = 0; j < 4; ++j) c[j] = (base + j < B) ? bcnt[base + j] : 0;
    int tsum = c[0] + c[1] + c[2] + c[3];
    ssc[t] = tsum; __syncthreads();
    int run = tsum;
    for (int off = 1; off < 256; off <<= 1) {
        int v = (t >= off) ? ssc[t - off] : 0;
        __syncthreads();
        run += v; ssc[t] = run;
        __syncthreads();
    }
    int ex = run - tsum;
    #pragma unroll
    for (int j = 0; j < 4; ++j) {
        int i = base + j;
        if (i <= B) { boff[i] = ex; bcur[i] = ex; }
        ex += c[j];
    }
}

// ---------- partition edges into bucket-grouped pairs (block-local counting sort) ----------
__global__ __launch_bounds__(256) void partition_kernel(const int* __restrict__ src,
                                                        const int* __restrict__ dst,
                                                        int* __restrict__ bcur,
                                                        u64* __restrict__ ep, int ne) {
    __shared__ int hcnt[BPAD];
    __shared__ int hoff[BPAD];
    __shared__ int gbase[BPAD];
    __shared__ u64 stage[CH];
    __shared__ int ssc[256];
    const int t = threadIdx.x;
    const int base = blockIdx.x * CH;
    const int cnt = min(CH, ne - base);
    for (int i = t; i < BPAD; i += 256) hcnt[i] = 0;
    __syncthreads();

    int myr[CH / 256];
    #pragma unroll
    for (int k = 0; k < CH / 256; ++k) {
        int i = t + k * 256;
        if (i < cnt) myr[k] = atomicAdd(&hcnt[dst[base + i] >> SH], 1);
    }
    __syncthreads();
    // exclusive scan hcnt -> hoff
    {
        int c0 = hcnt[t*4], c1 = hcnt[t*4+1], c2 = hcnt[t*4+2], c3 = hcnt[t*4+3];
        int tsum = c0 + c1 + c2 + c3;
        ssc[t] = tsum; __syncthreads();
        int run = tsum;
        for (int off = 1; off < 256; off <<= 1) {
            int v = (t >= off) ? ssc[t - off] : 0;
            __syncthreads();
            run += v; ssc[t] = run;
            __syncthreads();
        }
        int ex = run - tsum;
        hoff[t*4] = ex; ex += c0;
        hoff[t*4+1] = ex; ex += c1;
        hoff[t*4+2] = ex; ex += c2;
        hoff[t*4+3] = ex;
    }
    __syncthreads();
    // reserve global space (1 atomic per non-empty bucket per block)
    for (int b = t; b < BPAD; b += 256) {
        int c = hcnt[b];
        if (c) gbase[b] = atomicAdd(&bcur[b], c);
    }
    // scatter pairs into LDS, grouped by bucket
    #pragma unroll
    for (int k = 0; k < CH / 256; ++k) {
        int i = t + k * 256;
        if (i < cnt) {
            int s = src[base + i], d = dst[base + i];
            stage[hoff[d >> SH] + myr[k]] = ((u64)(unsigned int)d << 32) | (unsigned int)s;
        }
    }
    __syncthreads();
    // stream out: consecutive i -> contiguous runs per bucket
    for (int i = t; i < cnt; i += 256) {
        u64 pr = stage[i];
        int b = (int)(pr >> 32) >> SH;
        ep[gbase[b] + (i - hoff[b])] = pr;
    }
}

// ---------- per-bucket degree -> dinv ----------
__global__ __launch_bounds__(256) void bucket_deg_kernel(const u64* __restrict__ ep,
                                                         const int* __restrict__ boff,
                                                         float* __restrict__ dinv, int n) {
    __shared__ int cnt[BK];
    const int t = threadIdx.x, bId = blockIdx.x;
    if (t < BK) cnt[t] = 0;
    __syncthreads();
    int beg = boff[bId], end = boff[bId + 1];
    for (int p = beg + t; p < end; p += 256)
        atomicAdd(&cnt[((int)(ep[p] >> 32)) & (BK - 1)], 1);
    __syncthreads();
    if (t < BK) {
        int node = bId * BK + t;
        if (node < n) dinv[node] = rsqrtf((float)cnt[t] + 1.0f);
    }
}

// ---------- GEMM (n x K)@(K x 64) with dinv row-scale, bf16 out ----------
template <int K, typename TIn>
__global__ __launch_bounds__(256) void gemm_scale_kernel(const TIn* __restrict__ A,
                                                         const float* __restrict__ W,
                                                         const float* __restrict__ dinv,
                                                         u16* __restrict__ outbf, int n) {
    __shared__ float xs[16][K];
    const int t = threadIdx.x;
    const int row0 = blockIdx.x * 16;

    if constexpr (sizeof(TIn) == 4) {
        const float* Af = (const float*)A;
        if (row0 + 16 <= n) {
            const float4* Ap = (const float4*)(Af + (size_t)row0 * K);
            float4* xv = (float4*)&xs[0][0];
            for (int i = t; i < 16 * K / 4; i += 256) xv[i] = Ap[i];
        } else {
            for (int i = t; i < 16 * K; i += 256) {
                int r = i / K;
                (&xs[0][0])[i] = (row0 + r < n) ? Af[(size_t)row0 * K + i] : 0.f;
            }
        }
    } else {
        const u16* Ab = (const u16*)A;
        if (row0 + 16 <= n) {
            const ushort4* Ap = (const ushort4*)(Ab + (size_t)row0 * K);
            for (int i = t; i < 16 * K / 4; i += 256) {
                ushort4 v = Ap[i];
                float* dp = &(&xs[0][0])[i * 4];
                dp[0] = bf2f(v.x); dp[1] = bf2f(v.y); dp[2] = bf2f(v.z); dp[3] = bf2f(v.w);
            }
        } else {
            for (int i = t; i < 16 * K; i += 256) {
                int r = i / K;
                (&xs[0][0])[i] = (row0 + r < n) ? bf2f(Ab[(size_t)row0 * K + i]) : 0.f;
            }
        }
    }
    __syncthreads();

    const int c = t & 63, rg = t >> 6;
    float acc[4] = {0.f, 0.f, 0.f, 0.f};
    #pragma unroll 4
    for (int k = 0; k < K; ++k) {
        float w = W[k * HID + c];
        #pragma unroll
        for (int j = 0; j < 4; ++j) acc[j] += xs[rg + 4 * j][k] * w;
    }
    #pragma unroll
    for (int j = 0; j < 4; ++j) {
        int r = row0 + rg + 4 * j;
        if (r < n) outbf[(size_t)r * HID + c] = f2bf(acc[j] * dinv[r]);
    }
}

// ---------- bucket aggregation: LDS 128x64 f32 accumulator ----------
template <bool REDUCE>
__global__ __launch_bounds__(512) void agg_bucket_kernel(const u16* __restrict__ hp,
                                                         const u64* __restrict__ ep,
                                                         const int* __restrict__ boff,
                                                         const float* __restrict__ dinv,
                                                         const float* __restrict__ bias,
                                                         u16* __restrict__ h1out,
                                                         float* __restrict__ partials, int n) {
    __shared__ float acc[BK * HID];      // 32 KB
    __shared__ float sred[512];
    const int t = threadIdx.x;
    const int lane = t & 63;
    const int wid = t >> 6;              // 0..7
    const int bId = blockIdx.x;
    for (int i = t; i < BK * HID; i += 512) acc[i] = 0.f;
    __syncthreads();

    const int beg = boff[bId], end = boff[bId + 1];
    const int total = end - beg;
    const int per = (total + 7) >> 3;
    int p = beg + wid * per;
    int pe = min(p + per, end);

    for (; p + 4 <= pe; p += 4) {
        u64 pr0 = ep[p], pr1 = ep[p+1], pr2 = ep[p+2], pr3 = ep[p+3];
        int s0 = (int)(unsigned int)pr0, d0 = ((int)(pr0 >> 32)) & (BK - 1);
        int s1 = (int)(unsigned int)pr1, d1 = ((int)(pr1 >> 32)) & (BK - 1);
        int s2 = (int)(unsigned int)pr2, d2 = ((int)(pr2 >> 32)) & (BK - 1);
        int s3 = (int)(unsigned int)pr3, d3 = ((int)(pr3 >> 32)) & (BK - 1);
        float v0 = bf2f(hp[(size_t)s0 * HID + lane]);
        float v1 = bf2f(hp[(size_t)s1 * HID + lane]);
        float v2 = bf2f(hp[(size_t)s2 * HID + lane]);
        float v3 = bf2f(hp[(size_t)s3 * HID + lane]);
        atomicAdd(&acc[d0 * HID + lane], v0);
        atomicAdd(&acc[d1 * HID + lane], v1);
        atomicAdd(&acc[d2 * HID + lane], v2);
        atomicAdd(&acc[d3 * HID + lane], v3);
    }
    for (; p < pe; ++p) {
        u64 pr = ep[p];
        int s = (int)(unsigned int)pr, d = ((int)(pr >> 32)) & (BK - 1);
        atomicAdd(&acc[d * HID + lane], bf2f(hp[(size_t)s * HID + lane]));
    }
    __syncthreads();

    if constexpr (!REDUCE) {
        for (int r = wid; r < BK; r += 8) {
            int node = bId * BK + r;
            if (node < n) {
                float v = dinv[node] * (acc[r * HID + lane] + bf2f(hp[(size_t)node * HID + lane])) + bias[lane];
                h1out[(size_t)node * HID + lane] = f2bf(fmaxf(v, 0.f));
            }
        }
    } else {
        float tacc = 0.f;
        for (int r = wid; r < BK; r += 8) {
            int node = bId * BK + r;
            if (node < n) {
                float v = dinv[node] * (acc[r * HID + lane] + bf2f(hp[(size_t)node * HID + lane])) + bias[lane];
                tacc += fmaxf(v, 0.f);
            }
        }
        sred[t] = tacc; __syncthreads();
        if (t < 64) {
            float s = 0.f;
            #pragma unroll
            for (int w = 0; w < 8; ++w) s += sred[w * 64 + t];
            partials[bId * 64 + t] = s;
        }
    }
}

// ---------- final: out = sigmoid(dot(mean, Wf) + bf) ----------
__global__ __launch_bounds__(256) void final_partials_kernel(const float* __restrict__ partials, int nblk,
                                                             const float* __restrict__ Wf,
                                                             const float* __restrict__ bf_,
                                                             float* __restrict__ out, float invn) {
    __shared__ float sred[256];
    int t = threadIdx.x, lane = t & 63, grp = t >> 6;
    float a = 0.f;
    for (int bk = grp; bk < nblk; bk += 4) a += partials[bk * 64 + lane];
    sred[t] = a; __syncthreads();
    if (t < 64) {
        float v = (sred[t] + sred[t + 64] + sred[t + 128] + sred[t + 192]) * invn * Wf[t];
        #pragma unroll
        for (int off = 32; off; off >>= 1) v += __shfl_down(v, off);
        if (t == 0) out[0] = 1.f / (1.f + expf(-(v + bf_[0])));
    }
}

// ================= fallback (atomic aggregation, ~39 MB ws) =================
__global__ void deg_f_kernel(const int* __restrict__ dst, float* __restrict__ deg, int ne) {
    int i = blockIdx.x * blockDim.x + threadIdx.x, st = gridDim.x * blockDim.x;
    for (; i < ne; i += st) atomicAdd(&deg[dst[i]], 1.0f);
}
__global__ void dinvf_kernel(float* __restrict__ deg, int n) {
    int i = blockIdx.x * blockDim.x + threadIdx.x;
    if (i < n) deg[i] = rsqrtf(deg[i] + 1.0f);
}
__global__ __launch_bounds__(256) void aggregate_atomic_kernel(const u16* __restrict__ hp,
        const int* __restrict__ src, const int* __restrict__ dst,
        const float* __restrict__ dinv, float* __restrict__ outf, int ne) {
    size_t tt = (size_t)blockIdx.x * 256 + threadIdx.x;
    int e = (int)(tt >> 6), f = (int)(tt & 63);
    if (e >= ne) return;
    int s = src[e], d = dst[e];
    atomicAdd(&outf[(size_t)d * HID + f], bf2f(hp[(size_t)s * HID + f]) * dinv[d]);
}
__global__ void finalize1_fb_kernel(u16* __restrict__ hp, const float* __restrict__ agg,
                                    const float* __restrict__ dinv, const float* __restrict__ b, int n) {
    size_t i = (size_t)blockIdx.x * blockDim.x + threadIdx.x;
    if (i >= (size_t)n * HID) return;
    int node = (int)(i >> 6);
    float v = agg[i] + bf2f(hp[i]) * dinv[node] + b[i & 63];
    hp[i] = f2bf(fmaxf(v, 0.f));
}
__global__ __launch_bounds__(256) void finalize2_fb_kernel(const u16* __restrict__ hp,
        const float* __restrict__ agg, const float* __restrict__ dinv,
        const float* __restrict__ b, float* __restrict__ gsum, int n) {
    __shared__ float sred[256];
    const int t = threadIdx.x, c = t & 63;
    const size_t total = (size_t)n * HID;
    const size_t stride = (size_t)gridDim.x * blockDim.x;
    float acc = 0.f;
    for (size_t i = (size_t)blockIdx.x * blockDim.x + t; i < total; i += stride) {
        int node = (int)(i >> 6);
        acc += fmaxf(agg[i] + bf2f(hp[i]) * dinv[node] + b[c], 0.f);
    }
    sred[t] = acc; __syncthreads();
    if (t < 64) atomicAdd(&gsum[c], sred[t] + sred[t + 64] + sred[t + 128] + sred[t + 192]);
}
__global__ void final_gsum_kernel(const float* __restrict__ gsum, const float* __restrict__ Wf,
                                  const float* __restrict__ bf_, float* __restrict__ out, int n) {
    int lane = threadIdx.x;
    float v = (gsum[lane] / (float)n) * Wf[lane];
    #pragma unroll
    for (int off = 32; off; off >>= 1) v += __shfl_down(v, off);
    if (lane == 0) out[0] = 1.f / (1.f + expf(-(v + bf_[0])));
}

extern "C" void kernel_launch(void* const* d_in, const int* in_sizes, int n_in,
                              void* d_out, int out_size, void* d_ws, size_t ws_size,
                              hipStream_t stream) {
    const float* x  = (const float*)d_in[0];
    const int*   ei = (const int*)d_in[1];
    const float* W1 = (const float*)d_in[2];
    const float* b1 = (const float*)d_in[3];
    const float* W2 = (const float*)d_in[4];
    const float* b2 = (const float*)d_in[5];
    const float* Wf = (const float*)d_in[6];
    const float* bf_ = (const float*)d_in[7];
    float* out = (float*)d_out;

    const int n  = in_sizes[0] / 256;
    const int ne = in_sizes[1] / 2;
    const int* srcp = ei;
    const int* dstp = ei + ne;
    const int B = (n + BK - 1) / BK;

    // ---- primary layout (ep first for 8B alignment) ----
    char* p = (char*)d_ws;
    u64*   ep    = (u64*)p;   p += (size_t)ne * 8;
    int*   bcnt  = (int*)p;   p += BPAD * 4;
    int*   boff  = (int*)p;   p += (BPAD + 1) * 4;
    int*   bcur  = (int*)p;   p += BPAD * 4;
    float* dinv  = (float*)p; p += (size_t)n * 4;
    float* parts = (float*)p; p += (size_t)BPAD * 64 * 4;
    u16*   hp    = (u16*)p;   p += (size_t)n * HID * 2;
    u16*   h1    = (u16*)p;   p += (size_t)n * HID * 2;
    size_t need = (size_t)(p - (char*)d_ws);

    if (ws_size >= need) {
        hipMemsetAsync(bcnt, 0, BPAD * 4, stream);
        hist_kernel<<<512, 256, 0, stream>>>(dstp, bcnt, ne, B);
        bucket_scan_kernel<<<1, 256, 0, stream>>>(bcnt, boff, bcur, B);
        partition_kernel<<<(ne + CH - 1) / CH, 256, 0, stream>>>(srcp, dstp, bcur, ep, ne);
        bucket_deg_kernel<<<B, 256, 0, stream>>>(ep, boff, dinv, n);

        gemm_scale_kernel<256, float><<<(n + 15) / 16, 256, 0, stream>>>(x, W1, dinv, hp, n);
        agg_bucket_kernel<false><<<B, 512, 0, stream>>>(hp, ep, boff, dinv, b1, h1, nullptr, n);
        gemm_scale_kernel<64, u16><<<(n + 15) / 16, 256, 0, stream>>>(h1, W2, dinv, hp, n);
        agg_bucket_kernel<true><<<B, 512, 0, stream>>>(hp, ep, boff, dinv, b2, nullptr, parts, n);
        final_partials_kernel<<<1, 256, 0, stream>>>(parts, B, Wf, bf_, out, 1.0f / (float)n);
    } else {
        // ---- fallback: atomic aggregation, bf16 hp ----
        char* q = (char*)d_ws;
        float* dinvF = (float*)q; q += (size_t)n * 4;
        float* gsum  = (float*)q; q += 64 * 4;
        u16*   hpF   = (u16*)q;  q += (size_t)n * HID * 2;
        float* aggF  = (float*)q;

        hipMemsetAsync(dinvF, 0, ((size_t)n + 64) * 4, stream);
        deg_f_kernel<<<2048, 256, 0, stream>>>(dstp, dinvF, ne);
        dinvf_kernel<<<(n + 255) / 256, 256, 0, stream>>>(dinvF, n);

        gemm_scale_kernel<256, float><<<(n + 15) / 16, 256, 0, stream>>>(x, W1, dinvF, hpF, n);
        hipMemsetAsync(aggF, 0, (size_t)n * HID * 4, stream);
        aggregate_atomic_kernel<<<(int)(((size_t)ne * 64 + 255) / 256), 256, 0, stream>>>(hpF, srcp, dstp, dinvF, aggF, ne);
        finalize1_fb_kernel<<<(int)(((size_t)n * HID + 255) / 256), 256, 0, stream>>>(hpF, aggF, dinvF, b1, n);

        gemm_scale_kernel<64, u16><<<(n + 15) / 16, 256, 0, stream>>>(hpF, W2, dinvF, hpF, n);
        hipMemsetAsync(aggF, 0, (size_t)n * HID * 4, stream);
        aggregate_atomic_kernel<<<(int)(((size_t)ne * 64 + 255) / 256), 256, 0, stream>>>(hpF, srcp, dstp, dinvF, aggF, ne);
        finalize2_fb_kernel<<<2048, 256, 0, stream>>>(hpF, aggF, dinvF, b2, gsum, n);
        final_gsum_kernel<<<1, 64, 0, stream>>>(gsum, Wf, bf_, out, n);
    }
}

// Round 4
// 505.277 us; speedup vs baseline: 5.7464x; 5.7464x over previous
//
#include <hip/hip_runtime.h>

// GCN: h1 = relu(gcnconv(x,W1,b1)); h2 = relu(gcnconv(h1,W2,b2));
// out = sigmoid(mean(h2,0) @ Wf + bf)
// Factorization: hp = (x@W)*dinv[row];  out[d] = dinv[d]*(sum_{e:dst=d} hp[src] + hp[d]) + b
// CSR built via bucket partition (dst>>7) + per-bucket counting sort:
// no random global 4B writes outside a 16KB window, no global f32 atomics.

typedef unsigned int u32;
typedef unsigned short u16;

constexpr int HID  = 64;
constexpr int SH   = 7;          // bucket shift
constexpr int BK   = 128;        // nodes per bucket
constexpr int BPAD = 1024;       // padded bucket count (needs n <= 131072)
constexpr int CH   = 8192;       // edges per partition block
constexpr int NBLK2 = 1024;      // blocks for fused layer-2 agg + reduce

static __device__ __forceinline__ float bf2f(u16 v) {
    return __uint_as_float(((u32)v) << 16);
}
static __device__ __forceinline__ u16 f2bf(float f) {
    u32 u = __float_as_uint(f);
    return (u16)((u + 0x7FFFu + ((u >> 16) & 1u)) >> 16);
}

// ---------- bucket histogram (LDS-privatized) ----------
__global__ __launch_bounds__(256) void hist_kernel(const int* __restrict__ dst,
                                                   int* __restrict__ bcnt, int ne, int B) {
    __shared__ int h[BPAD];
    for (int i = threadIdx.x; i < BPAD; i += 256) h[i] = 0;
    __syncthreads();
    int i = blockIdx.x * 256 + threadIdx.x, st = gridDim.x * 256;
    for (; i < ne; i += st) atomicAdd(&h[dst[i] >> SH], 1);
    __syncthreads();
    for (int b = threadIdx.x; b < B; b += 256) if (h[b]) atomicAdd(&bcnt[b], h[b]);
}

// ---------- exclusive scan of bucket counts (single block) ----------
__global__ __launch_bounds__(256) void bucket_scan_kernel(const int* __restrict__ bcnt,
                                                          int* __restrict__ boff,
                                                          int* __restrict__ bcur, int B) {
    __shared__ int ssc[256];
    int t = threadIdx.x, base = t * 4;
    int c[4];
    #pragma unroll
    for (int j = 0; j < 4; ++j) c[j] = (base + j < B) ? bcnt[base + j] : 0;
    int tsum = c[0] + c[1] + c[2] + c[3];
    ssc[t] = tsum; __syncthreads();
    int run = tsum;
    for (int off = 1; off < 256; off <<= 1) {
        int v = (t >= off) ? ssc[t - off] : 0;
        __syncthreads();
        run += v; ssc[t] = run;
        __syncthreads();
    }
    int ex = run - tsum;
    #pragma unroll
    for (int j = 0; j < 4; ++j) {
        int i = base + j;
        if (i <= B) { boff[i] = ex; if (i < B) bcur[i] = ex; }
        ex += c[j];
    }
}

// ---------- partition: emit packed (d7<<20|src) grouped by bucket ----------
__global__ __launch_bounds__(256) void partition_kernel(const int* __restrict__ src,
                                                        const int* __restrict__ dst,
                                                        int* __restrict__ bcur,
                                                        u32* __restrict__ ep, int ne) {
    __shared__ int hcnt[BPAD];
    __shared__ int hoff[BPAD];
    __shared__ int gbase[BPAD];
    __shared__ u32 stage[CH];
    __shared__ int ssc[256];
    const int t = threadIdx.x;
    const int base = blockIdx.x * CH;
    const int cnt = min(CH, ne - base);
    for (int i = t; i < BPAD; i += 256) hcnt[i] = 0;
    __syncthreads();

    int myr[CH / 256];
    #pragma unroll
    for (int k = 0; k < CH / 256; ++k) {
        int i = t + k * 256;
        if (i < cnt) myr[k] = atomicAdd(&hcnt[dst[base + i] >> SH], 1);
    }
    __syncthreads();
    // exclusive scan hcnt -> hoff
    {
        int c0 = hcnt[t*4], c1 = hcnt[t*4+1], c2 = hcnt[t*4+2], c3 = hcnt[t*4+3];
        int tsum = c0 + c1 + c2 + c3;
        ssc[t] = tsum; __syncthreads();
        int run = tsum;
        for (int off = 1; off < 256; off <<= 1) {
            int v = (t >= off) ? ssc[t - off] : 0;
            __syncthreads();
            run += v; ssc[t] = run;
            __syncthreads();
        }
        int ex = run - tsum;
        hoff[t*4] = ex; ex += c0;
        hoff[t*4+1] = ex; ex += c1;
        hoff[t*4+2] = ex; ex += c2;
        hoff[t*4+3] = ex;
    }
    __syncthreads();
    // reserve global space (1 atomic per non-empty bucket per block)
    for (int b = t; b < BPAD; b += 256) {
        int c = hcnt[b];
        if (c) gbase[b] = atomicAdd(&bcur[b], c);
    }
    // scatter packed pairs into LDS, grouped by bucket
    #pragma unroll
    for (int k = 0; k < CH / 256; ++k) {
        int i = t + k * 256;
        if (i < cnt) {
            int s = src[base + i], d = dst[base + i];
            stage[hoff[d >> SH] + myr[k]] = ((u32)(d & (BK - 1)) << 20) | (u32)s;
        }
    }
    __syncthreads();
    // stream out coalesced; recover bucket by binary search in hoff
    for (int i = t; i < cnt; i += 256) {
        u32 v = stage[i];
        int lo = 0;
        #pragma unroll
        for (int s = 512; s; s >>= 1) {
            int m = lo + s;
            if (m < BPAD && hoff[m] <= i) lo = m;
        }
        ep[gbase[lo] + (i - hoff[lo])] = v;
    }
}

// ---------- per-bucket counting sort -> eidx (src, dst-sorted), rowend, dinv ----------
__global__ __launch_bounds__(256) void bucket_sort_kernel(const u32* __restrict__ ep,
                                                          const int* __restrict__ boff,
                                                          int* __restrict__ eidx,
                                                          int* __restrict__ rowend,
                                                          float* __restrict__ dinv, int n) {
    __shared__ int cnt[BK];
    __shared__ int sc[BK];
    __shared__ int cur[BK];
    const int t = threadIdx.x, b = blockIdx.x;
    const int beg = boff[b], end = boff[b + 1];
    if (t < BK) cnt[t] = 0;
    __syncthreads();
    for (int p = beg + t; p < end; p += 256) atomicAdd(&cnt[ep[p] >> 20], 1);
    __syncthreads();
    if (t < BK) sc[t] = cnt[t];
    __syncthreads();
    for (int o = 1; o < BK; o <<= 1) {
        int v = 0;
        if (t < BK && t >= o) v = sc[t - o];
        __syncthreads();
        if (t < BK) sc[t] += v;
        __syncthreads();
    }
    if (t < BK) {
        int node = b * BK + t;
        if (node < n) {
            rowend[node] = beg + sc[t];
            dinv[node] = rsqrtf((float)cnt[t] + 1.0f);
        }
        cur[t] = beg + sc[t] - cnt[t];
    }
    __syncthreads();
    for (int p = beg + t; p < end; p += 256) {
        u32 v = ep[p];
        int r = atomicAdd(&cur[v >> 20], 1);
        eidx[r] = (int)(v & 0xFFFFFu);
    }
}

// ---------- GEMM (n x K)@(K x 64) with dinv row-scale, bf16 out ----------
template <int K, typename TIn>
__global__ __launch_bounds__(256) void gemm_scale_kernel(const TIn* __restrict__ A,
                                                         const float* __restrict__ W,
                                                         const float* __restrict__ dinv,
                                                         u16* __restrict__ outbf, int n) {
    __shared__ float xs[16][K];
    const int t = threadIdx.x;
    const int row0 = blockIdx.x * 16;

    if constexpr (sizeof(TIn) == 4) {
        const float* Af = (const float*)A;
        if (row0 + 16 <= n) {
            const float4* Ap = (const float4*)(Af + (size_t)row0 * K);
            float4* xv = (float4*)&xs[0][0];
            for (int i = t; i < 16 * K / 4; i += 256) xv[i] = Ap[i];
        } else {
            for (int i = t; i < 16 * K; i += 256) {
                int r = i / K;
                (&xs[0][0])[i] = (row0 + r < n) ? Af[(size_t)row0 * K + i] : 0.f;
            }
        }
    } else {
        const u16* Ab = (const u16*)A;
        if (row0 + 16 <= n) {
            const ushort4* Ap = (const ushort4*)(Ab + (size_t)row0 * K);
            for (int i = t; i < 16 * K / 4; i += 256) {
                ushort4 v = Ap[i];
                float* dp = &(&xs[0][0])[i * 4];
                dp[0] = bf2f(v.x); dp[1] = bf2f(v.y); dp[2] = bf2f(v.z); dp[3] = bf2f(v.w);
            }
        } else {
            for (int i = t; i < 16 * K; i += 256) {
                int r = i / K;
                (&xs[0][0])[i] = (row0 + r < n) ? bf2f(Ab[(size_t)row0 * K + i]) : 0.f;
            }
        }
    }
    __syncthreads();

    const int c = t & 63, rg = t >> 6;
    float acc[4] = {0.f, 0.f, 0.f, 0.f};
    #pragma unroll 4
    for (int k = 0; k < K; ++k) {
        float w = W[k * HID + c];
        #pragma unroll
        for (int j = 0; j < 4; ++j) acc[j] += xs[rg + 4 * j][k] * w;
    }
    #pragma unroll
    for (int j = 0; j < 4; ++j) {
        int r = row0 + rg + 4 * j;
        if (r < n) outbf[(size_t)r * HID + c] = f2bf(acc[j] * dinv[r]);
    }
}

// ---------- CSR gather aggregation (layer 1): one wave per node ----------
__global__ __launch_bounds__(256) void agg_csr_kernel(const u16* __restrict__ hp,
                                                      const int* __restrict__ eidx,
                                                      const int* __restrict__ rowend,
                                                      const float* __restrict__ dinv,
                                                      const float* __restrict__ bias,
                                                      u16* __restrict__ out, int n) {
    int w = (blockIdx.x * 256 + threadIdx.x) >> 6;
    int lane = threadIdx.x & 63;
    if (w >= n) return;
    int beg = w ? rowend[w - 1] : 0;
    int end = rowend[w];
    float a0 = 0.f, a1 = 0.f, a2 = 0.f, a3 = 0.f;
    int p = beg;
    for (; p + 8 <= end; p += 8) {
        int s0 = eidx[p],   s1 = eidx[p+1], s2 = eidx[p+2], s3 = eidx[p+3];
        int s4 = eidx[p+4], s5 = eidx[p+5], s6 = eidx[p+6], s7 = eidx[p+7];
        float v0 = bf2f(hp[(size_t)s0 * HID + lane]);
        float v1 = bf2f(hp[(size_t)s1 * HID + lane]);
        float v2 = bf2f(hp[(size_t)s2 * HID + lane]);
        float v3 = bf2f(hp[(size_t)s3 * HID + lane]);
        float v4 = bf2f(hp[(size_t)s4 * HID + lane]);
        float v5 = bf2f(hp[(size_t)s5 * HID + lane]);
        float v6 = bf2f(hp[(size_t)s6 * HID + lane]);
        float v7 = bf2f(hp[(size_t)s7 * HID + lane]);
        a0 += v0; a1 += v1; a2 += v2; a3 += v3;
        a0 += v4; a1 += v5; a2 += v6; a3 += v7;
    }
    for (; p < end; ++p) a0 += bf2f(hp[(size_t)eidx[p] * HID + lane]);
    float acc = (a0 + a1) + (a2 + a3);
    float v = dinv[w] * (acc + bf2f(hp[(size_t)w * HID + lane])) + bias[lane];
    out[(size_t)w * HID + lane] = f2bf(fmaxf(v, 0.f));
}

// ---------- layer 2: CSR aggregation fused with graph-mean partials ----------
__global__ __launch_bounds__(256) void agg_csr_reduce_kernel(const u16* __restrict__ hp,
                                                             const int* __restrict__ eidx,
                                                             const int* __restrict__ rowend,
                                                             const float* __restrict__ dinv,
                                                             const float* __restrict__ bias,
                                                             float* __restrict__ partials, int n) {
    __shared__ float sred[256];
    int t = threadIdx.x, lane = t & 63;
    int wid = (blockIdx.x * 256 + t) >> 6;
    int wstride = gridDim.x * 4;
    float bl = bias[lane];
    float tacc = 0.f;
    for (int w = wid; w < n; w += wstride) {
        int beg = w ? rowend[w - 1] : 0;
        int end = rowend[w];
        float a0 = 0.f, a1 = 0.f, a2 = 0.f, a3 = 0.f;
        int p = beg;
        for (; p + 8 <= end; p += 8) {
            int s0 = eidx[p],   s1 = eidx[p+1], s2 = eidx[p+2], s3 = eidx[p+3];
            int s4 = eidx[p+4], s5 = eidx[p+5], s6 = eidx[p+6], s7 = eidx[p+7];
            float v0 = bf2f(hp[(size_t)s0 * HID + lane]);
            float v1 = bf2f(hp[(size_t)s1 * HID + lane]);
            float v2 = bf2f(hp[(size_t)s2 * HID + lane]);
            float v3 = bf2f(hp[(size_t)s3 * HID + lane]);
            float v4 = bf2f(hp[(size_t)s4 * HID + lane]);
            float v5 = bf2f(hp[(size_t)s5 * HID + lane]);
            float v6 = bf2f(hp[(size_t)s6 * HID + lane]);
            float v7 = bf2f(hp[(size_t)s7 * HID + lane]);
            a0 += v0; a1 += v1; a2 += v2; a3 += v3;
            a0 += v4; a1 += v5; a2 += v6; a3 += v7;
        }
        for (; p < end; ++p) a0 += bf2f(hp[(size_t)eidx[p] * HID + lane]);
        float acc = (a0 + a1) + (a2 + a3);
        tacc += fmaxf(dinv[w] * (acc + bf2f(hp[(size_t)w * HID + lane])) + bl, 0.f);
    }
    sred[t] = tacc; __syncthreads();
    if (t < 64) partials[blockIdx.x * 64 + t] = sred[t] + sred[t + 64] + sred[t + 128] + sred[t + 192];
}

// ---------- final: out = sigmoid(dot(mean, Wf) + bf) ----------
__global__ __launch_bounds__(256) void final_partials_kernel(const float* __restrict__ partials, int nblk,
                                                             const float* __restrict__ Wf,
                                                             const float* __restrict__ bf_,
                                                             float* __restrict__ out, float invn) {
    __shared__ float sred[256];
    int t = threadIdx.x, lane = t & 63, grp = t >> 6;
    float a = 0.f;
    for (int bk = grp; bk < nblk; bk += 4) a += partials[bk * 64 + lane];
    sred[t] = a; __syncthreads();
    if (t < 64) {
        float v = (sred[t] + sred[t + 64] + sred[t + 128] + sred[t + 192]) * invn * Wf[t];
        #pragma unroll
        for (int off = 32; off; off >>= 1) v += __shfl_down(v, off);
        if (t == 0) out[0] = 1.f / (1.f + expf(-(v + bf_[0])));
    }
}

// ================= fallback (atomic aggregation, ~39 MB ws) =================
__global__ void deg_f_kernel(const int* __restrict__ dst, float* __restrict__ deg, int ne) {
    int i = blockIdx.x * blockDim.x + threadIdx.x, st = gridDim.x * blockDim.x;
    for (; i < ne; i += st) atomicAdd(&deg[dst[i]], 1.0f);
}
__global__ void dinvf_kernel(float* __restrict__ deg, int n) {
    int i = blockIdx.x * blockDim.x + threadIdx.x;
    if (i < n) deg[i] = rsqrtf(deg[i] + 1.0f);
}
__global__ __launch_bounds__(256) void aggregate_atomic_kernel(const u16* __restrict__ hp,
        const int* __restrict__ src, const int* __restrict__ dst,
        const float* __restrict__ dinv, float* __restrict__ outf, int ne) {
    size_t tt = (size_t)blockIdx.x * 256 + threadIdx.x;
    int e = (int)(tt >> 6), f = (int)(tt & 63);
    if (e >= ne) return;
    int s = src[e], d = dst[e];
    atomicAdd(&outf[(size_t)d * HID + f], bf2f(hp[(size_t)s * HID + f]) * dinv[d]);
}
__global__ void finalize1_fb_kernel(u16* __restrict__ hp, const float* __restrict__ agg,
                                    const float* __restrict__ dinv, const float* __restrict__ b, int n) {
    size_t i = (size_t)blockIdx.x * blockDim.x + threadIdx.x;
    if (i >= (size_t)n * HID) return;
    int node = (int)(i >> 6);
    float v = agg[i] + bf2f(hp[i]) * dinv[node] + b[i & 63];
    hp[i] = f2bf(fmaxf(v, 0.f));
}
__global__ __launch_bounds__(256) void finalize2_fb_kernel(const u16* __restrict__ hp,
        const float* __restrict__ agg, const float* __restrict__ dinv,
        const float* __restrict__ b, float* __restrict__ gsum, int n) {
    __shared__ float sred[256];
    const int t = threadIdx.x, c = t & 63;
    const size_t total = (size_t)n * HID;
    const size_t stride = (size_t)gridDim.x * blockDim.x;
    float acc = 0.f;
    for (size_t i = (size_t)blockIdx.x * blockDim.x + t; i < total; i += stride) {
        int node = (int)(i >> 6);
        acc += fmaxf(agg[i] + bf2f(hp[i]) * dinv[node] + b[c], 0.f);
    }
    sred[t] = acc; __syncthreads();
    if (t < 64) atomicAdd(&gsum[c], sred[t] + sred[t + 64] + sred[t + 128] + sred[t + 192]);
}
__global__ void final_gsum_kernel(const float* __restrict__ gsum, const float* __restrict__ Wf,
                                  const float* __restrict__ bf_, float* __restrict__ out, int n) {
    int lane = threadIdx.x;
    float v = (gsum[lane] / (float)n) * Wf[lane];
    #pragma unroll
    for (int off = 32; off; off >>= 1) v += __shfl_down(v, off);
    if (lane == 0) out[0] = 1.f / (1.f + expf(-(v + bf_[0])));
}

extern "C" void kernel_launch(void* const* d_in, const int* in_sizes, int n_in,
                              void* d_out, int out_size, void* d_ws, size_t ws_size,
                              hipStream_t stream) {
    const float* x  = (const float*)d_in[0];
    const int*   ei = (const int*)d_in[1];
    const float* W1 = (const float*)d_in[2];
    const float* b1 = (const float*)d_in[3];
    const float* W2 = (const float*)d_in[4];
    const float* b2 = (const float*)d_in[5];
    const float* Wf = (const float*)d_in[6];
    const float* bf_ = (const float*)d_in[7];
    float* out = (float*)d_out;

    const int n  = in_sizes[0] / 256;
    const int ne = in_sizes[1] / 2;
    const int* srcp = ei;
    const int* dstp = ei + ne;
    const int B = (n + BK - 1) / BK;

    // ---- primary layout ----
    char* p = (char*)d_ws;
    u32*   ep     = (u32*)p;   p += (size_t)ne * 4;
    int*   bcnt   = (int*)p;   p += BPAD * 4;
    int*   boff   = (int*)p;   p += (BPAD + 1) * 4;
    int*   bcur   = (int*)p;   p += BPAD * 4;
    float* dinv   = (float*)p; p += (size_t)n * 4;
    int*   rowend = (int*)p;   p += (size_t)n * 4;
    int*   eidx   = (int*)p;   p += (size_t)ne * 4;
    float* parts  = (float*)p; p += (size_t)NBLK2 * 64 * 4;
    u16*   hp     = (u16*)p;   p += (size_t)n * HID * 2;
    u16*   h1     = (u16*)p;   p += (size_t)n * HID * 2;
    size_t need = (size_t)(p - (char*)d_ws);

    if (ws_size >= need && n <= (1 << 17)) {
        hipMemsetAsync(bcnt, 0, BPAD * 4, stream);
        hist_kernel<<<512, 256, 0, stream>>>(dstp, bcnt, ne, B);
        bucket_scan_kernel<<<1, 256, 0, stream>>>(bcnt, boff, bcur, B);
        partition_kernel<<<(ne + CH - 1) / CH, 256, 0, stream>>>(srcp, dstp, bcur, ep, ne);
        bucket_sort_kernel<<<B, 256, 0, stream>>>(ep, boff, eidx, rowend, dinv, n);

        gemm_scale_kernel<256, float><<<(n + 15) / 16, 256, 0, stream>>>(x, W1, dinv, hp, n);
        agg_csr_kernel<<<(n + 3) / 4, 256, 0, stream>>>(hp, eidx, rowend, dinv, b1, h1, n);
        gemm_scale_kernel<64, u16><<<(n + 15) / 16, 256, 0, stream>>>(h1, W2, dinv, hp, n);
        agg_csr_reduce_kernel<<<NBLK2, 256, 0, stream>>>(hp, eidx, rowend, dinv, b2, parts, n);
        final_partials_kernel<<<1, 256, 0, stream>>>(parts, NBLK2, Wf, bf_, out, 1.0f / (float)n);
    } else {
        // ---- fallback: atomic aggregation, bf16 hp ----
        char* q = (char*)d_ws;
        float* dinvF = (float*)q; q += (size_t)n * 4;
        float* gsum  = (float*)q; q += 64 * 4;
        u16*   hpF   = (u16*)q;  q += (size_t)n * HID * 2;
        float* aggF  = (float*)q;

        hipMemsetAsync(dinvF, 0, ((size_t)n + 64) * 4, stream);
        deg_f_kernel<<<2048, 256, 0, stream>>>(dstp, dinvF, ne);
        dinvf_kernel<<<(n + 255) / 256, 256, 0, stream>>>(dinvF, n);

        gemm_scale_kernel<256, float><<<(n + 15) / 16, 256, 0, stream>>>(x, W1, dinvF, hpF, n);
        hipMemsetAsync(aggF, 0, (size_t)n * HID * 4, stream);
        aggregate_atomic_kernel<<<(int)(((size_t)ne * 64 + 255) / 256), 256, 0, stream>>>(hpF, srcp, dstp, dinvF, aggF, ne);
        finalize1_fb_kernel<<<(int)(((size_t)n * HID + 255) / 256), 256, 0, stream>>>(hpF, aggF, dinvF, b1, n);

        gemm_scale_kernel<64, u16><<<(n + 15) / 16, 256, 0, stream>>>(hpF, W2, dinvF, hpF, n);
        hipMemsetAsync(aggF, 0, (size_t)n * HID * 4, stream);
        aggregate_atomic_kernel<<<(int)(((size_t)ne * 64 + 255) / 256), 256, 0, stream>>>(hpF, srcp, dstp, dinvF, aggF, ne);
        finalize2_fb_kernel<<<2048, 256, 0, stream>>>(hpF, aggF, dinvF, b2, gsum, n);
        final_gsum_kernel<<<1, 64, 0, stream>>>(gsum, Wf, bf_, out, n);
    }
}

// Round 5
// 448.874 us; speedup vs baseline: 6.4684x; 1.1257x over previous
//
#include <hip/hip_runtime.h>

// GCN: h1 = relu(gcnconv(x,W1,b1)); h2 = relu(gcnconv(h1,W2,b2));
// out = sigmoid(mean(h2,0) @ Wf + bf)
// Factorization: hp = (x@W)*dinv[row];  out[d] = dinv[d]*(sum_{e:dst=d} hp[src] + hp[d]) + b
// CSR built via bucket partition (dst>>7) + per-bucket counting sort with key
// (dst_local, src>>13): each row's edges are grouped by 1MB src-slabs of hp so
// concurrent waves gather from a moving window ("synchronized frontier").

typedef unsigned int u32;
typedef unsigned short u16;

constexpr int HID  = 64;
constexpr int SH   = 7;          // dst bucket shift
constexpr int BK   = 128;        // nodes per bucket
constexpr int BPAD = 1024;       // padded bucket count (needs n <= 131072)
constexpr int CH   = 8192;       // edges per partition block
constexpr int NSL  = 16;         // src slabs per bucket-sort
constexpr int SLSH = 13;         // src slab shift (8192 rows = 1MB bf16)
constexpr int NK   = BK * NSL;   // 2048 sort keys
constexpr int NBLK2 = 4096;      // blocks for fused layer-2 agg + reduce

static __device__ __forceinline__ float bf2f(u16 v) {
    return __uint_as_float(((u32)v) << 16);
}
static __device__ __forceinline__ u16 f2bf(float f) {
    u32 u = __float_as_uint(f);
    return (u16)((u + 0x7FFFu + ((u >> 16) & 1u)) >> 16);
}

// ---------- bucket histogram (LDS-privatized) ----------
__global__ __launch_bounds__(256) void hist_kernel(const int* __restrict__ dst,
                                                   int* __restrict__ bcnt, int ne, int B) {
    __shared__ int h[BPAD];
    for (int i = threadIdx.x; i < BPAD; i += 256) h[i] = 0;
    __syncthreads();
    int i = blockIdx.x * 256 + threadIdx.x, st = gridDim.x * 256;
    for (; i < ne; i += st) atomicAdd(&h[dst[i] >> SH], 1);
    __syncthreads();
    for (int b = threadIdx.x; b < B; b += 256) if (h[b]) atomicAdd(&bcnt[b], h[b]);
}

// ---------- exclusive scan of bucket counts (single block) ----------
__global__ __launch_bounds__(256) void bucket_scan_kernel(const int* __restrict__ bcnt,
                                                          int* __restrict__ boff,
                                                          int* __restrict__ bcur, int B) {
    __shared__ int ssc[256];
    int t = threadIdx.x, base = t * 4;
    int c[4];
    #pragma unroll
    for (int j = 0; j < 4; ++j) c[j] = (base + j < B) ? bcnt[base + j] : 0;
    int tsum = c[0] + c[1] + c[2] + c[3];
    ssc[t] = tsum; __syncthreads();
    int run = tsum;
    for (int off = 1; off < 256; off <<= 1) {
        int v = (t >= off) ? ssc[t - off] : 0;
        __syncthreads();
        run += v; ssc[t] = run;
        __syncthreads();
    }
    int ex = run - tsum;
    #pragma unroll
    for (int j = 0; j < 4; ++j) {
        int i = base + j;
        if (i <= B) { boff[i] = ex; if (i < B) bcur[i] = ex; }
        ex += c[j];
    }
}

// ---------- partition: emit packed (d7<<20|src) grouped by bucket ----------
__global__ __launch_bounds__(256) void partition_kernel(const int* __restrict__ src,
                                                        const int* __restrict__ dst,
                                                        int* __restrict__ bcur,
                                                        u32* __restrict__ ep, int ne) {
    __shared__ int hcnt[BPAD];
    __shared__ int hoff[BPAD];
    __shared__ int gbase[BPAD];
    __shared__ u32 stage[CH];
    __shared__ int ssc[256];
    const int t = threadIdx.x;
    const int base = blockIdx.x * CH;
    const int cnt = min(CH, ne - base);
    for (int i = t; i < BPAD; i += 256) hcnt[i] = 0;
    __syncthreads();

    int myr[CH / 256];
    #pragma unroll
    for (int k = 0; k < CH / 256; ++k) {
        int i = t + k * 256;
        if (i < cnt) myr[k] = atomicAdd(&hcnt[dst[base + i] >> SH], 1);
    }
    __syncthreads();
    // exclusive scan hcnt -> hoff
    {
        int c0 = hcnt[t*4], c1 = hcnt[t*4+1], c2 = hcnt[t*4+2], c3 = hcnt[t*4+3];
        int tsum = c0 + c1 + c2 + c3;
        ssc[t] = tsum; __syncthreads();
        int run = tsum;
        for (int off = 1; off < 256; off <<= 1) {
            int v = (t >= off) ? ssc[t - off] : 0;
            __syncthreads();
            run += v; ssc[t] = run;
            __syncthreads();
        }
        int ex = run - tsum;
        hoff[t*4] = ex; ex += c0;
        hoff[t*4+1] = ex; ex += c1;
        hoff[t*4+2] = ex; ex += c2;
        hoff[t*4+3] = ex;
    }
    __syncthreads();
    // reserve global space (1 atomic per non-empty bucket per block)
    for (int b = t; b < BPAD; b += 256) {
        int c = hcnt[b];
        if (c) gbase[b] = atomicAdd(&bcur[b], c);
    }
    // scatter packed pairs into LDS, grouped by bucket
    #pragma unroll
    for (int k = 0; k < CH / 256; ++k) {
        int i = t + k * 256;
        if (i < cnt) {
            int s = src[base + i], d = dst[base + i];
            stage[hoff[d >> SH] + myr[k]] = ((u32)(d & (BK - 1)) << 20) | (u32)s;
        }
    }
    __syncthreads();
    // stream out coalesced; recover bucket by binary search in hoff
    for (int i = t; i < cnt; i += 256) {
        u32 v = stage[i];
        int lo = 0;
        #pragma unroll
        for (int s = 512; s; s >>= 1) {
            int m = lo + s;
            if (m < BPAD && hoff[m] <= i) lo = m;
        }
        ep[gbase[lo] + (i - hoff[lo])] = v;
    }
}

// ---------- per-bucket counting sort by (dst_local, src_slab) ----------
__global__ __launch_bounds__(256) void bucket_sort_kernel(const u32* __restrict__ ep,
                                                          const int* __restrict__ boff,
                                                          int* __restrict__ eidx,
                                                          int* __restrict__ rowend,
                                                          float* __restrict__ dinv, int n) {
    __shared__ int cnt[NK];
    __shared__ int cur[NK];
    __shared__ int blk[256];
    const int t = threadIdx.x, b = blockIdx.x;
    const int beg = boff[b], end = boff[b + 1];
    for (int i = t; i < NK; i += 256) cnt[i] = 0;
    __syncthreads();
    for (int p = beg + t; p < end; p += 256) {
        u32 v = ep[p];
        atomicAdd(&cnt[(v >> 20) * NSL + ((v & 0xFFFFFu) >> SLSH)], 1);
    }
    __syncthreads();
    // exclusive scan of cnt[NK]; each thread owns 8 consecutive keys
    const int base = t * (NK / 256);
    int loc[NK / 256];
    int lsum = 0;
    #pragma unroll
    for (int j = 0; j < NK / 256; ++j) { loc[j] = cnt[base + j]; lsum += loc[j]; }
    blk[t] = lsum; __syncthreads();
    int run = lsum;
    for (int off = 1; off < 256; off <<= 1) {
        int v = (t >= off) ? blk[t - off] : 0;
        __syncthreads();
        run += v; blk[t] = run;
        __syncthreads();
    }
    int ex = run - lsum;
    #pragma unroll
    for (int j = 0; j < NK / 256; ++j) {
        cnt[base + j] = ex;
        cur[base + j] = beg + ex;
        ex += loc[j];
    }
    __syncthreads();
    // per-node rowend + dinv
    if (t < BK) {
        int node = b * BK + t;
        if (node < n) {
            int rs = cnt[t * NSL];
            int re = (t == BK - 1) ? (end - beg) : cnt[(t + 1) * NSL];
            rowend[node] = beg + re;
            dinv[node] = rsqrtf((float)(re - rs) + 1.0f);
        }
    }
    // scatter src into slab-grouped order
    for (int p = beg + t; p < end; p += 256) {
        u32 v = ep[p];
        int s = (int)(v & 0xFFFFFu);
        int r = atomicAdd(&cur[(v >> 20) * NSL + (s >> SLSH)], 1);
        eidx[r] = s;
    }
}

// ---------- GEMM (n x K)@(K x 64) with dinv row-scale, bf16 out ----------
template <int K, typename TIn>
__global__ __launch_bounds__(256) void gemm_scale_kernel(const TIn* __restrict__ A,
                                                         const float* __restrict__ W,
                                                         const float* __restrict__ dinv,
                                                         u16* __restrict__ outbf, int n) {
    __shared__ float xs[16][K];
    const int t = threadIdx.x;
    const int row0 = blockIdx.x * 16;

    if constexpr (sizeof(TIn) == 4) {
        const float* Af = (const float*)A;
        if (row0 + 16 <= n) {
            const float4* Ap = (const float4*)(Af + (size_t)row0 * K);
            float4* xv = (float4*)&xs[0][0];
            for (int i = t; i < 16 * K / 4; i += 256) xv[i] = Ap[i];
        } else {
            for (int i = t; i < 16 * K; i += 256) {
                int r = i / K;
                (&xs[0][0])[i] = (row0 + r < n) ? Af[(size_t)row0 * K + i] : 0.f;
            }
        }
    } else {
        const u16* Ab = (const u16*)A;
        if (row0 + 16 <= n) {
            const ushort4* Ap = (const ushort4*)(Ab + (size_t)row0 * K);
            for (int i = t; i < 16 * K / 4; i += 256) {
                ushort4 v = Ap[i];
                float* dp = &(&xs[0][0])[i * 4];
                dp[0] = bf2f(v.x); dp[1] = bf2f(v.y); dp[2] = bf2f(v.z); dp[3] = bf2f(v.w);
            }
        } else {
            for (int i = t; i < 16 * K; i += 256) {
                int r = i / K;
                (&xs[0][0])[i] = (row0 + r < n) ? bf2f(Ab[(size_t)row0 * K + i]) : 0.f;
            }
        }
    }
    __syncthreads();

    const int c = t & 63, rg = t >> 6;
    float acc[4] = {0.f, 0.f, 0.f, 0.f};
    #pragma unroll 4
    for (int k = 0; k < K; ++k) {
        float w = W[k * HID + c];
        #pragma unroll
        for (int j = 0; j < 4; ++j) acc[j] += xs[rg + 4 * j][k] * w;
    }
    #pragma unroll
    for (int j = 0; j < 4; ++j) {
        int r = row0 + rg + 4 * j;
        if (r < n) outbf[(size_t)r * HID + c] = f2bf(acc[j] * dinv[r]);
    }
}

// ---------- CSR gather aggregation (layer 1): one wave per node ----------
__global__ __launch_bounds__(256) void agg_csr_kernel(const u16* __restrict__ hp,
                                                      const int* __restrict__ eidx,
                                                      const int* __restrict__ rowend,
                                                      const float* __restrict__ dinv,
                                                      const float* __restrict__ bias,
                                                      u16* __restrict__ out, int n) {
    int w = (blockIdx.x * 256 + threadIdx.x) >> 6;
    int lane = threadIdx.x & 63;
    if (w >= n) return;
    int beg = w ? rowend[w - 1] : 0;
    int end = rowend[w];
    float a[4] = {0.f, 0.f, 0.f, 0.f};
    int p = beg;
    for (; p + 16 <= end; p += 16) {
        int s[16];
        #pragma unroll
        for (int j = 0; j < 16; ++j) s[j] = eidx[p + j];
        #pragma unroll
        for (int j = 0; j < 16; ++j) a[j & 3] += bf2f(hp[(size_t)s[j] * HID + lane]);
    }
    for (; p < end; ++p) a[0] += bf2f(hp[(size_t)eidx[p] * HID + lane]);
    float acc = (a[0] + a[1]) + (a[2] + a[3]);
    float v = dinv[w] * (acc + bf2f(hp[(size_t)w * HID + lane])) + bias[lane];
    out[(size_t)w * HID + lane] = f2bf(fmaxf(v, 0.f));
}

// ---------- layer 2: CSR aggregation fused with graph-mean partials ----------
__global__ __launch_bounds__(256) void agg_csr_reduce_kernel(const u16* __restrict__ hp,
                                                             const int* __restrict__ eidx,
                                                             const int* __restrict__ rowend,
                                                             const float* __restrict__ dinv,
                                                             const float* __restrict__ bias,
                                                             float* __restrict__ partials, int n) {
    __shared__ float sred[256];
    int t = threadIdx.x, lane = t & 63;
    int wid = (blockIdx.x * 256 + t) >> 6;
    int wstride = gridDim.x * 4;
    float bl = bias[lane];
    float tacc = 0.f;
    for (int w = wid; w < n; w += wstride) {
        int beg = w ? rowend[w - 1] : 0;
        int end = rowend[w];
        float a[4] = {0.f, 0.f, 0.f, 0.f};
        int p = beg;
        for (; p + 16 <= end; p += 16) {
            int s[16];
            #pragma unroll
            for (int j = 0; j < 16; ++j) s[j] = eidx[p + j];
            #pragma unroll
            for (int j = 0; j < 16; ++j) a[j & 3] += bf2f(hp[(size_t)s[j] * HID + lane]);
        }
        for (; p < end; ++p) a[0] += bf2f(hp[(size_t)eidx[p] * HID + lane]);
        float acc = (a[0] + a[1]) + (a[2] + a[3]);
        tacc += fmaxf(dinv[w] * (acc + bf2f(hp[(size_t)w * HID + lane])) + bl, 0.f);
    }
    sred[t] = tacc; __syncthreads();
    if (t < 64) partials[blockIdx.x * 64 + t] = sred[t] + sred[t + 64] + sred[t + 128] + sred[t + 192];
}

// ---------- two-stage partial reduction ----------
__global__ __launch_bounds__(256) void gsum_stage_kernel(const float* __restrict__ parts, int nblk,
                                                         float* __restrict__ gsum) {
    __shared__ float sred[256];
    int t = threadIdx.x, col = t & 63;
    float a = 0.f;
    for (int bk = blockIdx.x * 4 + (t >> 6); bk < nblk; bk += gridDim.x * 4)
        a += parts[bk * 64 + col];
    sred[t] = a; __syncthreads();
    if (t < 64) atomicAdd(&gsum[t], sred[t] + sred[t + 64] + sred[t + 128] + sred[t + 192]);
}

__global__ void final_gsum_kernel(const float* __restrict__ gsum, const float* __restrict__ Wf,
                                  const float* __restrict__ bf_, float* __restrict__ out, float invn) {
    int lane = threadIdx.x;
    float v = gsum[lane] * invn * Wf[lane];
    #pragma unroll
    for (int off = 32; off; off >>= 1) v += __shfl_down(v, off);
    if (lane == 0) out[0] = 1.f / (1.f + expf(-(v + bf_[0])));
}

// ================= fallback (atomic aggregation) =================
__global__ void deg_f_kernel(const int* __restrict__ dst, float* __restrict__ deg, int ne) {
    int i = blockIdx.x * blockDim.x + threadIdx.x, st = gridDim.x * blockDim.x;
    for (; i < ne; i += st) atomicAdd(&deg[dst[i]], 1.0f);
}
__global__ void dinvf_kernel(float* __restrict__ deg, int n) {
    int i = blockIdx.x * blockDim.x + threadIdx.x;
    if (i < n) deg[i] = rsqrtf(deg[i] + 1.0f);
}
__global__ __launch_bounds__(256) void aggregate_atomic_kernel(const u16* __restrict__ hp,
        const int* __restrict__ src, const int* __restrict__ dst,
        const float* __restrict__ dinv, float* __restrict__ outf, int ne) {
    size_t tt = (size_t)blockIdx.x * 256 + threadIdx.x;
    int e = (int)(tt >> 6), f = (int)(tt & 63);
    if (e >= ne) return;
    int s = src[e], d = dst[e];
    atomicAdd(&outf[(size_t)d * HID + f], bf2f(hp[(size_t)s * HID + f]) * dinv[d]);
}
__global__ void finalize1_fb_kernel(u16* __restrict__ hp, const float* __restrict__ agg,
                                    const float* __restrict__ dinv, const float* __restrict__ b, int n) {
    size_t i = (size_t)blockIdx.x * blockDim.x + threadIdx.x;
    if (i >= (size_t)n * HID) return;
    int node = (int)(i >> 6);
    float v = agg[i] + bf2f(hp[i]) * dinv[node] + b[i & 63];
    hp[i] = f2bf(fmaxf(v, 0.f));
}
__global__ __launch_bounds__(256) void finalize2_fb_kernel(const u16* __restrict__ hp,
        const float* __restrict__ agg, const float* __restrict__ dinv,
        const float* __restrict__ b, float* __restrict__ gsum, int n) {
    __shared__ float sred[256];
    const int t = threadIdx.x, c = t & 63;
    const size_t total = (size_t)n * HID;
    const size_t stride = (size_t)gridDim.x * blockDim.x;
    float acc = 0.f;
    for (size_t i = (size_t)blockIdx.x * blockDim.x + t; i < total; i += stride) {
        int node = (int)(i >> 6);
        acc += fmaxf(agg[i] + bf2f(hp[i]) * dinv[node] + b[c], 0.f);
    }
    sred[t] = acc; __syncthreads();
    if (t < 64) atomicAdd(&gsum[c], sred[t] + sred[t + 64] + sred[t + 128] + sred[t + 192]);
}
__global__ void final_gsum_fb_kernel(const float* __restrict__ gsum, const float* __restrict__ Wf,
                                     const float* __restrict__ bf_, float* __restrict__ out, int n) {
    int lane = threadIdx.x;
    float v = (gsum[lane] / (float)n) * Wf[lane];
    #pragma unroll
    for (int off = 32; off; off >>= 1) v += __shfl_down(v, off);
    if (lane == 0) out[0] = 1.f / (1.f + expf(-(v + bf_[0])));
}

extern "C" void kernel_launch(void* const* d_in, const int* in_sizes, int n_in,
                              void* d_out, int out_size, void* d_ws, size_t ws_size,
                              hipStream_t stream) {
    const float* x  = (const float*)d_in[0];
    const int*   ei = (const int*)d_in[1];
    const float* W1 = (const float*)d_in[2];
    const float* b1 = (const float*)d_in[3];
    const float* W2 = (const float*)d_in[4];
    const float* b2 = (const float*)d_in[5];
    const float* Wf = (const float*)d_in[6];
    const float* bf_ = (const float*)d_in[7];
    float* out = (float*)d_out;

    const int n  = in_sizes[0] / 256;
    const int ne = in_sizes[1] / 2;
    const int* srcp = ei;
    const int* dstp = ei + ne;
    const int B = (n + BK - 1) / BK;

    // ---- primary layout ----
    char* p = (char*)d_ws;
    u32*   ep     = (u32*)p;   p += (size_t)ne * 4;
    int*   bcnt   = (int*)p;   p += BPAD * 4;
    int*   boff   = (int*)p;   p += (BPAD + 1) * 4;
    int*   bcur   = (int*)p;   p += BPAD * 4;
    float* dinv   = (float*)p; p += (size_t)n * 4;
    int*   rowend = (int*)p;   p += (size_t)n * 4;
    float* gsum   = (float*)p; p += 64 * 4;
    int*   eidx   = (int*)p;   p += (size_t)ne * 4;
    float* parts  = (float*)p; p += (size_t)NBLK2 * 64 * 4;
    u16*   hp     = (u16*)p;   p += (size_t)n * HID * 2;
    u16*   h1     = (u16*)p;   p += (size_t)n * HID * 2;
    size_t need = (size_t)(p - (char*)d_ws);

    if (ws_size >= need && n <= (1 << 17)) {
        hipMemsetAsync(bcnt, 0, BPAD * 4, stream);
        hipMemsetAsync(gsum, 0, 64 * 4, stream);
        hist_kernel<<<512, 256, 0, stream>>>(dstp, bcnt, ne, B);
        bucket_scan_kernel<<<1, 256, 0, stream>>>(bcnt, boff, bcur, B);
        partition_kernel<<<(ne + CH - 1) / CH, 256, 0, stream>>>(srcp, dstp, bcur, ep, ne);
        bucket_sort_kernel<<<B, 256, 0, stream>>>(ep, boff, eidx, rowend, dinv, n);

        gemm_scale_kernel<256, float><<<(n + 15) / 16, 256, 0, stream>>>(x, W1, dinv, hp, n);
        agg_csr_kernel<<<(n + 3) / 4, 256, 0, stream>>>(hp, eidx, rowend, dinv, b1, h1, n);
        gemm_scale_kernel<64, u16><<<(n + 15) / 16, 256, 0, stream>>>(h1, W2, dinv, hp, n);
        agg_csr_reduce_kernel<<<NBLK2, 256, 0, stream>>>(hp, eidx, rowend, dinv, b2, parts, n);
        gsum_stage_kernel<<<128, 256, 0, stream>>>(parts, NBLK2, gsum);
        final_gsum_kernel<<<1, 64, 0, stream>>>(gsum, Wf, bf_, out, 1.0f / (float)n);
    } else {
        // ---- fallback: atomic aggregation, bf16 hp ----
        char* q = (char*)d_ws;
        float* dinvF = (float*)q; q += (size_t)n * 4;
        float* gsumF = (float*)q; q += 64 * 4;
        u16*   hpF   = (u16*)q;  q += (size_t)n * HID * 2;
        float* aggF  = (float*)q;

        hipMemsetAsync(dinvF, 0, ((size_t)n + 64) * 4, stream);
        deg_f_kernel<<<2048, 256, 0, stream>>>(dstp, dinvF, ne);
        dinvf_kernel<<<(n + 255) / 256, 256, 0, stream>>>(dinvF, n);

        gemm_scale_kernel<256, float><<<(n + 15) / 16, 256, 0, stream>>>(x, W1, dinvF, hpF, n);
        hipMemsetAsync(aggF, 0, (size_t)n * HID * 4, stream);
        aggregate_atomic_kernel<<<(int)(((size_t)ne * 64 + 255) / 256), 256, 0, stream>>>(hpF, srcp, dstp, dinvF, aggF, ne);
        finalize1_fb_kernel<<<(int)(((size_t)n * HID + 255) / 256), 256, 0, stream>>>(hpF, aggF, dinvF, b1, n);

        gemm_scale_kernel<64, u16><<<(n + 15) / 16, 256, 0, stream>>>(hpF, W2, dinvF, hpF, n);
        hipMemsetAsync(aggF, 0, (size_t)n * HID * 4, stream);
        aggregate_atomic_kernel<<<(int)(((size_t)ne * 64 + 255) / 256), 256, 0, stream>>>(hpF, srcp, dstp, dinvF, aggF, ne);
        finalize2_fb_kernel<<<2048, 256, 0, stream>>>(hpF, aggF, dinvF, b2, gsumF, n);
        final_gsum_fb_kernel<<<1, 64, 0, stream>>>(gsumF, Wf, bf_, out, n);
    }
}

// Round 6
// 425.708 us; speedup vs baseline: 6.8204x; 1.0544x over previous
//
#include <hip/hip_runtime.h>

// GCN: h1 = relu(gcnconv(x,W1,b1)); h2 = relu(gcnconv(h1,W2,b2));
// out = sigmoid(mean(h2,0) @ Wf + bf)
// Factorization: hp = (x@W)*dinv[row];  out[d] = dinv[d]*(sum_{e:dst=d} hp[src] + hp[d]) + b
// hp/h1 stored as fp8 e4m3 (HW cvt): 6.4 MB working set -> L2-friendly gathers.
// CSR built via bucket partition (dst>>7) + per-bucket counting sort.

typedef unsigned int u32;
typedef unsigned short u16;
typedef unsigned char u8;

constexpr int HID  = 64;
constexpr int SH   = 7;          // dst bucket shift
constexpr int BK   = 128;        // nodes per bucket
constexpr int BPAD = 1024;       // padded bucket count (needs n <= 131072)
constexpr int CH   = 8192;       // edges per partition block
constexpr int NBLK2 = 4096;      // blocks for fused layer-2 agg + reduce

static __device__ __forceinline__ u8 f2fp8(float f) {
    int p = __builtin_amdgcn_cvt_pk_fp8_f32(f, f, 0, false);
    return (u8)(p & 0xFF);
}
static __device__ __forceinline__ float fp82f(u8 v) {
    return __builtin_amdgcn_cvt_f32_fp8((int)v, 0);
}

// ---------- bucket histogram (LDS-privatized) ----------
__global__ __launch_bounds__(256) void hist_kernel(const int* __restrict__ dst,
                                                   int* __restrict__ bcnt, int ne, int B) {
    __shared__ int h[BPAD];
    for (int i = threadIdx.x; i < BPAD; i += 256) h[i] = 0;
    __syncthreads();
    int i = blockIdx.x * 256 + threadIdx.x, st = gridDim.x * 256;
    for (; i < ne; i += st) atomicAdd(&h[dst[i] >> SH], 1);
    __syncthreads();
    for (int b = threadIdx.x; b < B; b += 256) if (h[b]) atomicAdd(&bcnt[b], h[b]);
}

// ---------- exclusive scan of bucket counts (single block) ----------
__global__ __launch_bounds__(256) void bucket_scan_kernel(const int* __restrict__ bcnt,
                                                          int* __restrict__ boff,
                                                          int* __restrict__ bcur, int B) {
    __shared__ int ssc[256];
    int t = threadIdx.x, base = t * 4;
    int c[4];
    #pragma unroll
    for (int j = 0; j < 4; ++j) c[j] = (base + j < B) ? bcnt[base + j] : 0;
    int tsum = c[0] + c[1] + c[2] + c[3];
    ssc[t] = tsum; __syncthreads();
    int run = tsum;
    for (int off = 1; off < 256; off <<= 1) {
        int v = (t >= off) ? ssc[t - off] : 0;
        __syncthreads();
        run += v; ssc[t] = run;
        __syncthreads();
    }
    int ex = run - tsum;
    #pragma unroll
    for (int j = 0; j < 4; ++j) {
        int i = base + j;
        if (i <= B) { boff[i] = ex; if (i < B) bcur[i] = ex; }
        ex += c[j];
    }
}

// ---------- partition: emit packed (d7<<20|src) grouped by bucket ----------
__global__ __launch_bounds__(256) void partition_kernel(const int* __restrict__ src,
                                                        const int* __restrict__ dst,
                                                        int* __restrict__ bcur,
                                                        u32* __restrict__ ep, int ne) {
    __shared__ int hcnt[BPAD];
    __shared__ int hoff[BPAD];
    __shared__ int gbase[BPAD];
    __shared__ u32 stage[CH];
    __shared__ int ssc[256];
    const int t = threadIdx.x;
    const int base = blockIdx.x * CH;
    const int cnt = min(CH, ne - base);
    for (int i = t; i < BPAD; i += 256) hcnt[i] = 0;
    __syncthreads();

    int myr[CH / 256];
    #pragma unroll
    for (int k = 0; k < CH / 256; ++k) {
        int i = t + k * 256;
        if (i < cnt) myr[k] = atomicAdd(&hcnt[dst[base + i] >> SH], 1);
    }
    __syncthreads();
    // exclusive scan hcnt -> hoff
    {
        int c0 = hcnt[t*4], c1 = hcnt[t*4+1], c2 = hcnt[t*4+2], c3 = hcnt[t*4+3];
        int tsum = c0 + c1 + c2 + c3;
        ssc[t] = tsum; __syncthreads();
        int run = tsum;
        for (int off = 1; off < 256; off <<= 1) {
            int v = (t >= off) ? ssc[t - off] : 0;
            __syncthreads();
            run += v; ssc[t] = run;
            __syncthreads();
        }
        int ex = run - tsum;
        hoff[t*4] = ex; ex += c0;
        hoff[t*4+1] = ex; ex += c1;
        hoff[t*4+2] = ex; ex += c2;
        hoff[t*4+3] = ex;
    }
    __syncthreads();
    // reserve global space (1 atomic per non-empty bucket per block)
    for (int b = t; b < BPAD; b += 256) {
        int c = hcnt[b];
        if (c) gbase[b] = atomicAdd(&bcur[b], c);
    }
    // scatter packed pairs into LDS, grouped by bucket
    #pragma unroll
    for (int k = 0; k < CH / 256; ++k) {
        int i = t + k * 256;
        if (i < cnt) {
            int s = src[base + i], d = dst[base + i];
            stage[hoff[d >> SH] + myr[k]] = ((u32)(d & (BK - 1)) << 20) | (u32)s;
        }
    }
    __syncthreads();
    // stream out coalesced; recover bucket by binary search in hoff
    for (int i = t; i < cnt; i += 256) {
        u32 v = stage[i];
        int lo = 0;
        #pragma unroll
        for (int s = 512; s; s >>= 1) {
            int m = lo + s;
            if (m < BPAD && hoff[m] <= i) lo = m;
        }
        ep[gbase[lo] + (i - hoff[lo])] = v;
    }
}

// ---------- per-bucket counting sort -> eidx (src, dst-sorted), rowend, dinv ----------
__global__ __launch_bounds__(256) void bucket_sort_kernel(const u32* __restrict__ ep,
                                                          const int* __restrict__ boff,
                                                          int* __restrict__ eidx,
                                                          int* __restrict__ rowend,
                                                          float* __restrict__ dinv, int n) {
    __shared__ int cnt[BK];
    __shared__ int sc[BK];
    __shared__ int cur[BK];
    const int t = threadIdx.x, b = blockIdx.x;
    const int beg = boff[b], end = boff[b + 1];
    if (t < BK) cnt[t] = 0;
    __syncthreads();
    for (int p = beg + t; p < end; p += 256) atomicAdd(&cnt[ep[p] >> 20], 1);
    __syncthreads();
    if (t < BK) sc[t] = cnt[t];
    __syncthreads();
    for (int o = 1; o < BK; o <<= 1) {
        int v = 0;
        if (t < BK && t >= o) v = sc[t - o];
        __syncthreads();
        if (t < BK) sc[t] += v;
        __syncthreads();
    }
    if (t < BK) {
        int node = b * BK + t;
        if (node < n) {
            rowend[node] = beg + sc[t];
            dinv[node] = rsqrtf((float)cnt[t] + 1.0f);
        }
        cur[t] = beg + sc[t] - cnt[t];
    }
    __syncthreads();
    for (int p = beg + t; p < end; p += 256) {
        u32 v = ep[p];
        int r = atomicAdd(&cur[v >> 20], 1);
        eidx[r] = (int)(v & 0xFFFFFu);
    }
}

// ---------- GEMM (n x K)@(K x 64) with dinv row-scale, fp8 out ----------
// TIn = float (layer 1) or u8 fp8 (layer 2 input)
template <int K, typename TIn>
__global__ __launch_bounds__(256) void gemm_scale_kernel(const TIn* __restrict__ A,
                                                         const float* __restrict__ W,
                                                         const float* __restrict__ dinv,
                                                         u8* __restrict__ out8, int n) {
    __shared__ float xs[16][K];
    const int t = threadIdx.x;
    const int row0 = blockIdx.x * 16;

    if constexpr (sizeof(TIn) == 4) {
        const float* Af = (const float*)A;
        if (row0 + 16 <= n) {
            const float4* Ap = (const float4*)(Af + (size_t)row0 * K);
            float4* xv = (float4*)&xs[0][0];
            for (int i = t; i < 16 * K / 4; i += 256) xv[i] = Ap[i];
        } else {
            for (int i = t; i < 16 * K; i += 256) {
                int r = i / K;
                (&xs[0][0])[i] = (row0 + r < n) ? Af[(size_t)row0 * K + i] : 0.f;
            }
        }
    } else {
        const u8* Ab = (const u8*)A;
        if (row0 + 16 <= n) {
            const u32* Ap = (const u32*)(Ab + (size_t)row0 * K);
            for (int i = t; i < 16 * K / 4; i += 256) {
                u32 v = Ap[i];
                float* dp = &(&xs[0][0])[i * 4];
                dp[0] = __builtin_amdgcn_cvt_f32_fp8((int)v, 0);
                dp[1] = __builtin_amdgcn_cvt_f32_fp8((int)v, 1);
                dp[2] = __builtin_amdgcn_cvt_f32_fp8((int)v, 2);
                dp[3] = __builtin_amdgcn_cvt_f32_fp8((int)v, 3);
            }
        } else {
            for (int i = t; i < 16 * K; i += 256) {
                int r = i / K;
                (&xs[0][0])[i] = (row0 + r < n) ? fp82f(Ab[(size_t)row0 * K + i]) : 0.f;
            }
        }
    }
    __syncthreads();

    const int c = t & 63, rg = t >> 6;
    float acc[4] = {0.f, 0.f, 0.f, 0.f};
    #pragma unroll 4
    for (int k = 0; k < K; ++k) {
        float w = W[k * HID + c];
        #pragma unroll
        for (int j = 0; j < 4; ++j) acc[j] += xs[rg + 4 * j][k] * w;
    }
    #pragma unroll
    for (int j = 0; j < 4; ++j) {
        int r = row0 + rg + 4 * j;
        if (r < n) out8[(size_t)r * HID + c] = f2fp8(acc[j] * dinv[r]);
    }
}

// ---------- CSR gather aggregation (layer 1): one wave per node, fp8 in/out ----------
__global__ __launch_bounds__(256) void agg_csr_kernel(const u8* __restrict__ hp,
                                                      const int* __restrict__ eidx,
                                                      const int* __restrict__ rowend,
                                                      const float* __restrict__ dinv,
                                                      const float* __restrict__ bias,
                                                      u8* __restrict__ out, int n) {
    int w = (blockIdx.x * 256 + threadIdx.x) >> 6;
    int lane = threadIdx.x & 63;
    if (w >= n) return;
    int beg = w ? rowend[w - 1] : 0;
    int end = rowend[w];
    float a[4] = {0.f, 0.f, 0.f, 0.f};
    int p = beg;
    for (; p + 16 <= end; p += 16) {
        int s[16];
        #pragma unroll
        for (int j = 0; j < 16; ++j) s[j] = eidx[p + j];
        u8 v[16];
        #pragma unroll
        for (int j = 0; j < 16; ++j) v[j] = hp[s[j] * HID + lane];
        #pragma unroll
        for (int j = 0; j < 16; ++j) a[j & 3] += fp82f(v[j]);
    }
    for (; p < end; ++p) a[0] += fp82f(hp[eidx[p] * HID + lane]);
    float acc = (a[0] + a[1]) + (a[2] + a[3]);
    float v = dinv[w] * (acc + fp82f(hp[w * HID + lane])) + bias[lane];
    out[(size_t)w * HID + lane] = f2fp8(fmaxf(v, 0.f));
}

// ---------- layer 2: CSR aggregation fused with graph-mean partials ----------
__global__ __launch_bounds__(256) void agg_csr_reduce_kernel(const u8* __restrict__ hp,
                                                             const int* __restrict__ eidx,
                                                             const int* __restrict__ rowend,
                                                             const float* __restrict__ dinv,
                                                             const float* __restrict__ bias,
                                                             float* __restrict__ partials, int n) {
    __shared__ float sred[256];
    int t = threadIdx.x, lane = t & 63;
    int wid = (blockIdx.x * 256 + t) >> 6;
    int wstride = gridDim.x * 4;
    float bl = bias[lane];
    float tacc = 0.f;
    for (int w = wid; w < n; w += wstride) {
        int beg = w ? rowend[w - 1] : 0;
        int end = rowend[w];
        float a[4] = {0.f, 0.f, 0.f, 0.f};
        int p = beg;
        for (; p + 16 <= end; p += 16) {
            int s[16];
            #pragma unroll
            for (int j = 0; j < 16; ++j) s[j] = eidx[p + j];
            u8 v[16];
            #pragma unroll
            for (int j = 0; j < 16; ++j) v[j] = hp[s[j] * HID + lane];
            #pragma unroll
            for (int j = 0; j < 16; ++j) a[j & 3] += fp82f(v[j]);
        }
        for (; p < end; ++p) a[0] += fp82f(hp[eidx[p] * HID + lane]);
        float acc = (a[0] + a[1]) + (a[2] + a[3]);
        tacc += fmaxf(dinv[w] * (acc + fp82f(hp[w * HID + lane])) + bl, 0.f);
    }
    sred[t] = tacc; __syncthreads();
    if (t < 64) partials[blockIdx.x * 64 + t] = sred[t] + sred[t + 64] + sred[t + 128] + sred[t + 192];
}

// ---------- two-stage partial reduction ----------
__global__ __launch_bounds__(256) void gsum_stage_kernel(const float* __restrict__ parts, int nblk,
                                                         float* __restrict__ gsum) {
    __shared__ float sred[256];
    int t = threadIdx.x, col = t & 63;
    float a = 0.f;
    for (int bk = blockIdx.x * 4 + (t >> 6); bk < nblk; bk += gridDim.x * 4)
        a += parts[bk * 64 + col];
    sred[t] = a; __syncthreads();
    if (t < 64) atomicAdd(&gsum[t], sred[t] + sred[t + 64] + sred[t + 128] + sred[t + 192]);
}

__global__ void final_gsum_kernel(const float* __restrict__ gsum, const float* __restrict__ Wf,
                                  const float* __restrict__ bf_, float* __restrict__ out, float invn) {
    int lane = threadIdx.x;
    float v = gsum[lane] * invn * Wf[lane];
    #pragma unroll
    for (int off = 32; off; off >>= 1) v += __shfl_down(v, off);
    if (lane == 0) out[0] = 1.f / (1.f + expf(-(v + bf_[0])));
}

// ================= fallback (atomic aggregation, fp8 hp) =================
__global__ void deg_f_kernel(const int* __restrict__ dst, float* __restrict__ deg, int ne) {
    int i = blockIdx.x * blockDim.x + threadIdx.x, st = gridDim.x * blockDim.x;
    for (; i < ne; i += st) atomicAdd(&deg[dst[i]], 1.0f);
}
__global__ void dinvf_kernel(float* __restrict__ deg, int n) {
    int i = blockIdx.x * blockDim.x + threadIdx.x;
    if (i < n) deg[i] = rsqrtf(deg[i] + 1.0f);
}
__global__ __launch_bounds__(256) void aggregate_atomic_kernel(const u8* __restrict__ hp,
        const int* __restrict__ src, const int* __restrict__ dst,
        const float* __restrict__ dinv, float* __restrict__ outf, int ne) {
    size_t tt = (size_t)blockIdx.x * 256 + threadIdx.x;
    int e = (int)(tt >> 6), f = (int)(tt & 63);
    if (e >= ne) return;
    int s = src[e], d = dst[e];
    atomicAdd(&outf[(size_t)d * HID + f], fp82f(hp[s * HID + f]) * dinv[d]);
}
__global__ void finalize1_fb_kernel(u8* __restrict__ hp, const float* __restrict__ agg,
                                    const float* __restrict__ dinv, const float* __restrict__ b, int n) {
    size_t i = (size_t)blockIdx.x * blockDim.x + threadIdx.x;
    if (i >= (size_t)n * HID) return;
    int node = (int)(i >> 6);
    float v = agg[i] + fp82f(hp[i]) * dinv[node] + b[i & 63];
    hp[i] = f2fp8(fmaxf(v, 0.f));
}
__global__ __launch_bounds__(256) void finalize2_fb_kernel(const u8* __restrict__ hp,
        const float* __restrict__ agg, const float* __restrict__ dinv,
        const float* __restrict__ b, float* __restrict__ gsum, int n) {
    __shared__ float sred[256];
    const int t = threadIdx.x, c = t & 63;
    const size_t total = (size_t)n * HID;
    const size_t stride = (size_t)gridDim.x * blockDim.x;
    float acc = 0.f;
    for (size_t i = (size_t)blockIdx.x * blockDim.x + t; i < total; i += stride) {
        int node = (int)(i >> 6);
        acc += fmaxf(agg[i] + fp82f(hp[i]) * dinv[node] + b[c], 0.f);
    }
    sred[t] = acc; __syncthreads();
    if (t < 64) atomicAdd(&gsum[c], sred[t] + sred[t + 64] + sred[t + 128] + sred[t + 192]);
}
__global__ void final_gsum_fb_kernel(const float* __restrict__ gsum, const float* __restrict__ Wf,
                                     const float* __restrict__ bf_, float* __restrict__ out, int n) {
    int lane = threadIdx.x;
    float v = (gsum[lane] / (float)n) * Wf[lane];
    #pragma unroll
    for (int off = 32; off; off >>= 1) v += __shfl_down(v, off);
    if (lane == 0) out[0] = 1.f / (1.f + expf(-(v + bf_[0])));
}

extern "C" void kernel_launch(void* const* d_in, const int* in_sizes, int n_in,
                              void* d_out, int out_size, void* d_ws, size_t ws_size,
                              hipStream_t stream) {
    const float* x  = (const float*)d_in[0];
    const int*   ei = (const int*)d_in[1];
    const float* W1 = (const float*)d_in[2];
    const float* b1 = (const float*)d_in[3];
    const float* W2 = (const float*)d_in[4];
    const float* b2 = (const float*)d_in[5];
    const float* Wf = (const float*)d_in[6];
    const float* bf_ = (const float*)d_in[7];
    float* out = (float*)d_out;

    const int n  = in_sizes[0] / 256;
    const int ne = in_sizes[1] / 2;
    const int* srcp = ei;
    const int* dstp = ei + ne;
    const int B = (n + BK - 1) / BK;

    // ---- primary layout ----
    char* p = (char*)d_ws;
    u32*   ep     = (u32*)p;   p += (size_t)ne * 4;
    int*   bcnt   = (int*)p;   p += BPAD * 4;
    int*   boff   = (int*)p;   p += (BPAD + 1) * 4;
    int*   bcur   = (int*)p;   p += BPAD * 4;
    float* dinv   = (float*)p; p += (size_t)n * 4;
    int*   rowend = (int*)p;   p += (size_t)n * 4;
    float* gsum   = (float*)p; p += 64 * 4;
    int*   eidx   = (int*)p;   p += (size_t)ne * 4;
    float* parts  = (float*)p; p += (size_t)NBLK2 * 64 * 4;
    u8*    hp     = (u8*)p;    p += (size_t)n * HID;
    u8*    h1     = (u8*)p;    p += (size_t)n * HID;
    size_t need = (size_t)(p - (char*)d_ws);

    if (ws_size >= need && n <= (1 << 17)) {
        hipMemsetAsync(bcnt, 0, BPAD * 4, stream);
        hipMemsetAsync(gsum, 0, 64 * 4, stream);
        hist_kernel<<<512, 256, 0, stream>>>(dstp, bcnt, ne, B);
        bucket_scan_kernel<<<1, 256, 0, stream>>>(bcnt, boff, bcur, B);
        partition_kernel<<<(ne + CH - 1) / CH, 256, 0, stream>>>(srcp, dstp, bcur, ep, ne);
        bucket_sort_kernel<<<B, 256, 0, stream>>>(ep, boff, eidx, rowend, dinv, n);

        gemm_scale_kernel<256, float><<<(n + 15) / 16, 256, 0, stream>>>(x, W1, dinv, hp, n);
        agg_csr_kernel<<<(n + 3) / 4, 256, 0, stream>>>(hp, eidx, rowend, dinv, b1, h1, n);
        gemm_scale_kernel<64, u8><<<(n + 15) / 16, 256, 0, stream>>>(h1, W2, dinv, hp, n);
        agg_csr_reduce_kernel<<<NBLK2, 256, 0, stream>>>(hp, eidx, rowend, dinv, b2, parts, n);
        gsum_stage_kernel<<<128, 256, 0, stream>>>(parts, NBLK2, gsum);
        final_gsum_kernel<<<1, 64, 0, stream>>>(gsum, Wf, bf_, out, 1.0f / (float)n);
    } else {
        // ---- fallback: atomic aggregation, fp8 hp ----
        char* q = (char*)d_ws;
        float* dinvF = (float*)q; q += (size_t)n * 4;
        float* gsumF = (float*)q; q += 64 * 4;
        u8*    hpF   = (u8*)q;   q += (size_t)n * HID;
        float* aggF  = (float*)q;

        hipMemsetAsync(dinvF, 0, ((size_t)n + 64) * 4, stream);
        deg_f_kernel<<<2048, 256, 0, stream>>>(dstp, dinvF, ne);
        dinvf_kernel<<<(n + 255) / 256, 256, 0, stream>>>(dinvF, n);

        gemm_scale_kernel<256, float><<<(n + 15) / 16, 256, 0, stream>>>(x, W1, dinvF, hpF, n);
        hipMemsetAsync(aggF, 0, (size_t)n * HID * 4, stream);
        aggregate_atomic_kernel<<<(int)(((size_t)ne * 64 + 255) / 256), 256, 0, stream>>>(hpF, srcp, dstp, dinvF, aggF, ne);
        finalize1_fb_kernel<<<(int)(((size_t)n * HID + 255) / 256), 256, 0, stream>>>(hpF, aggF, dinvF, b1, n);

        gemm_scale_kernel<64, u8><<<(n + 15) / 16, 256, 0, stream>>>(hpF, W2, dinvF, hpF, n);
        hipMemsetAsync(aggF, 0, (size_t)n * HID * 4, stream);
        aggregate_atomic_kernel<<<(int)(((size_t)ne * 64 + 255) / 256), 256, 0, stream>>>(hpF, srcp, dstp, dinvF, aggF, ne);
        finalize2_fb_kernel<<<2048, 256, 0, stream>>>(hpF, aggF, dinvF, b2, gsumF, n);
        final_gsum_fb_kernel<<<1, 64, 0, stream>>>(gsumF, Wf, bf_, out, n);
    }
}

// Round 9
// 364.956 us; speedup vs baseline: 7.9558x; 1.1665x over previous
//
#include <hip/hip_runtime.h>

// GCN: h1 = relu(gcnconv(x,W1,b1)); h2 = relu(gcnconv(h1,W2,b2));
// out = sigmoid(mean(h2,0) @ Wf + bf)
// hp = (x@W)*dinv[row] stored fp8 e4m3; aggregation = CSR gather (bucket-built).
// GEMMs use MFMA 16x16x32 bf16 with fragment-prepacked W.

typedef unsigned int u32;
typedef unsigned short u16;
typedef unsigned char u8;
typedef short s16x8 __attribute__((ext_vector_type(8)));   // 8 bf16 bit-patterns
typedef __bf16 bf16x8 __attribute__((ext_vector_type(8))); // MFMA operand type
typedef float f32x4 __attribute__((ext_vector_type(4)));

constexpr int HID  = 64;
constexpr int SH   = 7;          // dst bucket shift
constexpr int BK   = 128;        // nodes per bucket
constexpr int BPAD = 1024;       // padded bucket count (needs n <= 131072)
constexpr int CH   = 8192;       // edges per partition block
constexpr int NBLK2 = 4096;      // blocks for fused layer-2 agg + reduce

static __device__ __forceinline__ u8 f2fp8(float f) {
    int p = __builtin_amdgcn_cvt_pk_fp8_f32(f, f, 0, false);
    return (u8)(p & 0xFF);
}
static __device__ __forceinline__ float fp82f(u8 v) {
    return __builtin_amdgcn_cvt_f32_fp8((int)v, 0);
}
static __device__ __forceinline__ u16 f2bf(float f) {
    u32 u = __float_as_uint(f);
    return (u16)((u + 0x7FFFu + ((u >> 16) & 1u)) >> 16);
}

// ---------- bucket histogram (LDS-privatized) ----------
__global__ __launch_bounds__(256) void hist_kernel(const int* __restrict__ dst,
                                                   int* __restrict__ bcnt, int ne, int B) {
    __shared__ int h[BPAD];
    for (int i = threadIdx.x; i < BPAD; i += 256) h[i] = 0;
    __syncthreads();
    int i = blockIdx.x * 256 + threadIdx.x, st = gridDim.x * 256;
    for (; i < ne; i += st) atomicAdd(&h[dst[i] >> SH], 1);
    __syncthreads();
    for (int b = threadIdx.x; b < B; b += 256) if (h[b]) atomicAdd(&bcnt[b], h[b]);
}

// ---------- exclusive scan of bucket counts (single block) ----------
__global__ __launch_bounds__(256) void bucket_scan_kernel(const int* __restrict__ bcnt,
                                                          int* __restrict__ boff,
                                                          int* __restrict__ bcur, int B) {
    __shared__ int ssc[256];
    int t = threadIdx.x, base = t * 4;
    int c[4];
    #pragma unroll
    for (int j = 0; j < 4; ++j) c[j] = (base + j < B) ? bcnt[base + j] : 0;
    int tsum = c[0] + c[1] + c[2] + c[3];
    ssc[t] = tsum; __syncthreads();
    int run = tsum;
    for (int off = 1; off < 256; off <<= 1) {
        int v = (t >= off) ? ssc[t - off] : 0;
        __syncthreads();
        run += v; ssc[t] = run;
        __syncthreads();
    }
    int ex = run - tsum;
    #pragma unroll
    for (int j = 0; j < 4; ++j) {
        int i = base + j;
        if (i <= B) { boff[i] = ex; if (i < B) bcur[i] = ex; }
        ex += c[j];
    }
}

// ---------- partition: emit packed (d7<<20|src) grouped by bucket ----------
__global__ __launch_bounds__(256) void partition_kernel(const int* __restrict__ src,
                                                        const int* __restrict__ dst,
                                                        int* __restrict__ bcur,
                                                        u32* __restrict__ ep, int ne) {
    __shared__ int hcnt[BPAD];
    __shared__ int hoff[BPAD];
    __shared__ int gbase[BPAD];
    __shared__ u32 stage[CH];
    __shared__ int ssc[256];
    const int t = threadIdx.x;
    const int base = blockIdx.x * CH;
    const int cnt = min(CH, ne - base);
    for (int i = t; i < BPAD; i += 256) hcnt[i] = 0;
    __syncthreads();

    int myr[CH / 256];
    #pragma unroll
    for (int k = 0; k < CH / 256; ++k) {
        int i = t + k * 256;
        if (i < cnt) myr[k] = atomicAdd(&hcnt[dst[base + i] >> SH], 1);
    }
    __syncthreads();
    {
        int c0 = hcnt[t*4], c1 = hcnt[t*4+1], c2 = hcnt[t*4+2], c3 = hcnt[t*4+3];
        int tsum = c0 + c1 + c2 + c3;
        ssc[t] = tsum; __syncthreads();
        int run = tsum;
        for (int off = 1; off < 256; off <<= 1) {
            int v = (t >= off) ? ssc[t - off] : 0;
            __syncthreads();
            run += v; ssc[t] = run;
            __syncthreads();
        }
        int ex = run - tsum;
        hoff[t*4] = ex; ex += c0;
        hoff[t*4+1] = ex; ex += c1;
        hoff[t*4+2] = ex; ex += c2;
        hoff[t*4+3] = ex;
    }
    __syncthreads();
    for (int b = t; b < BPAD; b += 256) {
        int c = hcnt[b];
        if (c) gbase[b] = atomicAdd(&bcur[b], c);
    }
    #pragma unroll
    for (int k = 0; k < CH / 256; ++k) {
        int i = t + k * 256;
        if (i < cnt) {
            int s = src[base + i], d = dst[base + i];
            stage[hoff[d >> SH] + myr[k]] = ((u32)(d & (BK - 1)) << 20) | (u32)s;
        }
    }
    __syncthreads();
    for (int i = t; i < cnt; i += 256) {
        u32 v = stage[i];
        int lo = 0;
        #pragma unroll
        for (int s = 512; s; s >>= 1) {
            int m = lo + s;
            if (m < BPAD && hoff[m] <= i) lo = m;
        }
        ep[gbase[lo] + (i - hoff[lo])] = v;
    }
}

// ---------- per-bucket counting sort -> eidx (src, dst-sorted), rowend, dinv ----------
__global__ __launch_bounds__(256) void bucket_sort_kernel(const u32* __restrict__ ep,
                                                          const int* __restrict__ boff,
                                                          int* __restrict__ eidx,
                                                          int* __restrict__ rowend,
                                                          float* __restrict__ dinv, int n) {
    __shared__ int cnt[BK];
    __shared__ int sc[BK];
    __shared__ int cur[BK];
    const int t = threadIdx.x, b = blockIdx.x;
    const int beg = boff[b], end = boff[b + 1];
    if (t < BK) cnt[t] = 0;
    __syncthreads();
    for (int p = beg + t; p < end; p += 256) atomicAdd(&cnt[ep[p] >> 20], 1);
    __syncthreads();
    if (t < BK) sc[t] = cnt[t];
    __syncthreads();
    for (int o = 1; o < BK; o <<= 1) {
        int v = 0;
        if (t < BK && t >= o) v = sc[t - o];
        __syncthreads();
        if (t < BK) sc[t] += v;
        __syncthreads();
    }
    if (t < BK) {
        int node = b * BK + t;
        if (node < n) {
            rowend[node] = beg + sc[t];
            dinv[node] = rsqrtf((float)cnt[t] + 1.0f);
        }
        cur[t] = beg + sc[t] - cnt[t];
    }
    __syncthreads();
    for (int p = beg + t; p < end; p += 256) {
        u32 v = ep[p];
        int r = atomicAdd(&cur[v >> 20], 1);
        eidx[r] = (int)(v & 0xFFFFFu);
    }
}

// ---------- W pack: wpack[kk][nt][lane][i] = bf16 W[kk*32+(lane>>4)*8+i][nt*16+(lane&15)] ----------
template <int K>
__global__ void pack_w_kernel(const float* __restrict__ W, u16* __restrict__ wpack) {
    int i = blockIdx.x * 256 + threadIdx.x;
    if (i >= K * 64) return;
    int e = i & 7, lane = (i >> 3) & 63, nt = (i >> 9) & 3, kk = i >> 11;
    int k = kk * 32 + (lane >> 4) * 8 + e;
    int c = nt * 16 + (lane & 15);
    wpack[i] = f2bf(W[k * HID + c]);
}

// ---------- MFMA GEMM: out8[r][c] = fp8( (A[r,:]@W[:,c]) * dinv[r] ) ----------
// one wave per 16-row tile; 4 n-tiles of 16; K/32 k-steps
template <int K, typename TIn>
__global__ __launch_bounds__(256) void mfma_gemm_kernel(const TIn* __restrict__ A,
                                                        const u16* __restrict__ wpack,
                                                        const float* __restrict__ dinv,
                                                        u8* __restrict__ out8, int n) {
    const int t = threadIdx.x;
    const int lane = t & 63;
    const int wid = t >> 6;
    const int r16 = lane & 15;
    const int kgrp = lane >> 4;
    const int ntiles = (n + 15) >> 4;
    for (int tile = blockIdx.x * 4 + wid; tile < ntiles; tile += gridDim.x * 4) {
        const int row0 = tile * 16;
        const int arow = row0 + r16;
        f32x4 acc[4] = {f32x4{0,0,0,0}, f32x4{0,0,0,0}, f32x4{0,0,0,0}, f32x4{0,0,0,0}};
        #pragma unroll
        for (int kk = 0; kk < K / 32; ++kk) {
            s16x8 abits;
            if constexpr (sizeof(TIn) == 4) {
                const float* Af = (const float*)A;
                if (arow < n) {
                    const float4* p0 = (const float4*)(Af + (size_t)arow * K + kk * 32 + kgrp * 8);
                    float4 v0 = p0[0], v1 = p0[1];
                    abits[0] = (short)f2bf(v0.x); abits[1] = (short)f2bf(v0.y);
                    abits[2] = (short)f2bf(v0.z); abits[3] = (short)f2bf(v0.w);
                    abits[4] = (short)f2bf(v1.x); abits[5] = (short)f2bf(v1.y);
                    abits[6] = (short)f2bf(v1.z); abits[7] = (short)f2bf(v1.w);
                } else {
                    #pragma unroll
                    for (int j = 0; j < 8; ++j) abits[j] = 0;
                }
            } else {
                const u8* Ab = (const u8*)A;
                u32 w0 = 0, w1 = 0;
                if (arow < n) {
                    const u32* p0 = (const u32*)(Ab + (size_t)arow * K + kk * 32 + kgrp * 8);
                    w0 = p0[0]; w1 = p0[1];
                }
                abits[0] = (short)f2bf(__builtin_amdgcn_cvt_f32_fp8((int)w0, 0));
                abits[1] = (short)f2bf(__builtin_amdgcn_cvt_f32_fp8((int)w0, 1));
                abits[2] = (short)f2bf(__builtin_amdgcn_cvt_f32_fp8((int)w0, 2));
                abits[3] = (short)f2bf(__builtin_amdgcn_cvt_f32_fp8((int)w0, 3));
                abits[4] = (short)f2bf(__builtin_amdgcn_cvt_f32_fp8((int)w1, 0));
                abits[5] = (short)f2bf(__builtin_amdgcn_cvt_f32_fp8((int)w1, 1));
                abits[6] = (short)f2bf(__builtin_amdgcn_cvt_f32_fp8((int)w1, 2));
                abits[7] = (short)f2bf(__builtin_amdgcn_cvt_f32_fp8((int)w1, 3));
            }
            bf16x8 afrag = __builtin_bit_cast(bf16x8, abits);
            const u16* wp = wpack + ((size_t)(kk * 4) * 64 + lane) * 8;
            #pragma unroll
            for (int nt = 0; nt < 4; ++nt) {
                bf16x8 bfrag = *(const bf16x8*)(wp + (size_t)nt * 64 * 8);
                acc[nt] = __builtin_amdgcn_mfma_f32_16x16x32_bf16(afrag, bfrag, acc[nt], 0, 0, 0);
            }
        }
        #pragma unroll
        for (int reg = 0; reg < 4; ++reg) {
            int r = row0 + kgrp * 4 + reg;
            if (r < n) {
                float dv = dinv[r];
                #pragma unroll
                for (int nt = 0; nt < 4; ++nt)
                    out8[(size_t)r * HID + nt * 16 + r16] = f2fp8(acc[nt][reg] * dv);
            }
        }
    }
}

// ---------- CSR gather aggregation (layer 1): one wave per node, fp8 in/out ----------
__global__ __launch_bounds__(256) void agg_csr_kernel(const u8* __restrict__ hp,
                                                      const int* __restrict__ eidx,
                                                      const int* __restrict__ rowend,
                                                      const float* __restrict__ dinv,
                                                      const float* __restrict__ bias,
                                                      u8* __restrict__ out, int n) {
    int w = (blockIdx.x * 256 + threadIdx.x) >> 6;
    int lane = threadIdx.x & 63;
    if (w >= n) return;
    int beg = w ? rowend[w - 1] : 0;
    int end = rowend[w];
    float a[4] = {0.f, 0.f, 0.f, 0.f};
    int p = beg;
    for (; p + 16 <= end; p += 16) {
        int s[16];
        #pragma unroll
        for (int j = 0; j < 16; ++j) s[j] = eidx[p + j];
        u8 v[16];
        #pragma unroll
        for (int j = 0; j < 16; ++j) v[j] = hp[s[j] * HID + lane];
        #pragma unroll
        for (int j = 0; j < 16; ++j) a[j & 3] += fp82f(v[j]);
    }
    for (; p < end; ++p) a[0] += fp82f(hp[eidx[p] * HID + lane]);
    float acc = (a[0] + a[1]) + (a[2] + a[3]);
    float v = dinv[w] * (acc + fp82f(hp[w * HID + lane])) + bias[lane];
    out[(size_t)w * HID + lane] = f2fp8(fmaxf(v, 0.f));
}

// ---------- layer 2: CSR aggregation fused with graph-mean partials ----------
__global__ __launch_bounds__(256) void agg_csr_reduce_kernel(const u8* __restrict__ hp,
                                                             const int* __restrict__ eidx,
                                                             const int* __restrict__ rowend,
                                                             const float* __restrict__ dinv,
                                                             const float* __restrict__ bias,
                                                             float* __restrict__ partials, int n) {
    __shared__ float sred[256];
    int t = threadIdx.x, lane = t & 63;
    int wid = (blockIdx.x * 256 + t) >> 6;
    int wstride = gridDim.x * 4;
    float bl = bias[lane];
    float tacc = 0.f;
    for (int w = wid; w < n; w += wstride) {
        int beg = w ? rowend[w - 1] : 0;
        int end = rowend[w];
        float a[4] = {0.f, 0.f, 0.f, 0.f};
        int p = beg;
        for (; p + 16 <= end; p += 16) {
            int s[16];
            #pragma unroll
            for (int j = 0; j < 16; ++j) s[j] = eidx[p + j];
            u8 v[16];
            #pragma unroll
            for (int j = 0; j < 16; ++j) v[j] = hp[s[j] * HID + lane];
            #pragma unroll
            for (int j = 0; j < 16; ++j) a[j & 3] += fp82f(v[j]);
        }
        for (; p < end; ++p) a[0] += fp82f(hp[eidx[p] * HID + lane]);
        float acc = (a[0] + a[1]) + (a[2] + a[3]);
        tacc += fmaxf(dinv[w] * (acc + fp82f(hp[w * HID + lane])) + bl, 0.f);
    }
    sred[t] = tacc; __syncthreads();
    if (t < 64) partials[blockIdx.x * 64 + t] = sred[t] + sred[t + 64] + sred[t + 128] + sred[t + 192];
}

// ---------- two-stage partial reduction ----------
__global__ __launch_bounds__(256) void gsum_stage_kernel(const float* __restrict__ parts, int nblk,
                                                         float* __restrict__ gsum) {
    __shared__ float sred[256];
    int t = threadIdx.x, col = t & 63;
    float a = 0.f;
    for (int bk = blockIdx.x * 4 + (t >> 6); bk < nblk; bk += gridDim.x * 4)
        a += parts[bk * 64 + col];
    sred[t] = a; __syncthreads();
    if (t < 64) atomicAdd(&gsum[t], sred[t] + sred[t + 64] + sred[t + 128] + sred[t + 192]);
}

__global__ void final_gsum_kernel(const float* __restrict__ gsum, const float* __restrict__ Wf,
                                  const float* __restrict__ bf_, float* __restrict__ out, float invn) {
    int lane = threadIdx.x;
    float v = gsum[lane] * invn * Wf[lane];
    #pragma unroll
    for (int off = 32; off; off >>= 1) v += __shfl_down(v, off);
    if (lane == 0) out[0] = 1.f / (1.f + expf(-(v + bf_[0])));
}

// ================= fallback (atomic aggregation, fp8 hp, VALU gemm) =================
template <int K, typename TIn>
__global__ __launch_bounds__(256) void gemm_scale_kernel(const TIn* __restrict__ A,
                                                         const float* __restrict__ W,
                                                         const float* __restrict__ dinv,
                                                         u8* __restrict__ out8, int n) {
    __shared__ float xs[16][K];
    const int t = threadIdx.x;
    const int row0 = blockIdx.x * 16;
    if constexpr (sizeof(TIn) == 4) {
        const float* Af = (const float*)A;
        for (int i = t; i < 16 * K; i += 256) {
            int r = i / K;
            (&xs[0][0])[i] = (row0 + r < n) ? Af[(size_t)row0 * K + i] : 0.f;
        }
    } else {
        const u8* Ab = (const u8*)A;
        for (int i = t; i < 16 * K; i += 256) {
            int r = i / K;
            (&xs[0][0])[i] = (row0 + r < n) ? fp82f(Ab[(size_t)row0 * K + i]) : 0.f;
        }
    }
    __syncthreads();
    const int c = t & 63, rg = t >> 6;
    float acc[4] = {0.f, 0.f, 0.f, 0.f};
    #pragma unroll 4
    for (int k = 0; k < K; ++k) {
        float w = W[k * HID + c];
        #pragma unroll
        for (int j = 0; j < 4; ++j) acc[j] += xs[rg + 4 * j][k] * w;
    }
    #pragma unroll
    for (int j = 0; j < 4; ++j) {
        int r = row0 + rg + 4 * j;
        if (r < n) out8[(size_t)r * HID + c] = f2fp8(acc[j] * dinv[r]);
    }
}
__global__ void deg_f_kernel(const int* __restrict__ dst, float* __restrict__ deg, int ne) {
    int i = blockIdx.x * blockDim.x + threadIdx.x, st = gridDim.x * blockDim.x;
    for (; i < ne; i += st) atomicAdd(&deg[dst[i]], 1.0f);
}
__global__ void dinvf_kernel(float* __restrict__ deg, int n) {
    int i = blockIdx.x * blockDim.x + threadIdx.x;
    if (i < n) deg[i] = rsqrtf(deg[i] + 1.0f);
}
__global__ __launch_bounds__(256) void aggregate_atomic_kernel(const u8* __restrict__ hp,
        const int* __restrict__ src, const int* __restrict__ dst,
        const float* __restrict__ dinv, float* __restrict__ outf, int ne) {
    size_t tt = (size_t)blockIdx.x * 256 + threadIdx.x;
    int e = (int)(tt >> 6), f = (int)(tt & 63);
    if (e >= ne) return;
    int s = src[e], d = dst[e];
    atomicAdd(&outf[(size_t)d * HID + f], fp82f(hp[s * HID + f]) * dinv[d]);
}
__global__ void finalize1_fb_kernel(u8* __restrict__ hp, const float* __restrict__ agg,
                                    const float* __restrict__ dinv, const float* __restrict__ b, int n) {
    size_t i = (size_t)blockIdx.x * blockDim.x + threadIdx.x;
    if (i >= (size_t)n * HID) return;
    int node = (int)(i >> 6);
    float v = agg[i] + fp82f(hp[i]) * dinv[node] + b[i & 63];
    hp[i] = f2fp8(fmaxf(v, 0.f));
}
__global__ __launch_bounds__(256) void finalize2_fb_kernel(const u8* __restrict__ hp,
        const float* __restrict__ agg, const float* __restrict__ dinv,
        const float* __restrict__ b, float* __restrict__ gsum, int n) {
    __shared__ float sred[256];
    const int t = threadIdx.x, c = t & 63;
    const size_t total = (size_t)n * HID;
    const size_t stride = (size_t)gridDim.x * blockDim.x;
    float acc = 0.f;
    for (size_t i = (size_t)blockIdx.x * blockDim.x + t; i < total; i += stride) {
        int node = (int)(i >> 6);
        acc += fmaxf(agg[i] + fp82f(hp[i]) * dinv[node] + b[c], 0.f);
    }
    sred[t] = acc; __syncthreads();
    if (t < 64) atomicAdd(&gsum[c], sred[t] + sred[t + 64] + sred[t + 128] + sred[t + 192]);
}
__global__ void final_gsum_fb_kernel(const float* __restrict__ gsum, const float* __restrict__ Wf,
                                     const float* __restrict__ bf_, float* __restrict__ out, int n) {
    int lane = threadIdx.x;
    float v = (gsum[lane] / (float)n) * Wf[lane];
    #pragma unroll
    for (int off = 32; off; off >>= 1) v += __shfl_down(v, off);
    if (lane == 0) out[0] = 1.f / (1.f + expf(-(v + bf_[0])));
}

extern "C" void kernel_launch(void* const* d_in, const int* in_sizes, int n_in,
                              void* d_out, int out_size, void* d_ws, size_t ws_size,
                              hipStream_t stream) {
    const float* x  = (const float*)d_in[0];
    const int*   ei = (const int*)d_in[1];
    const float* W1 = (const float*)d_in[2];
    const float* b1 = (const float*)d_in[3];
    const float* W2 = (const float*)d_in[4];
    const float* b2 = (const float*)d_in[5];
    const float* Wf = (const float*)d_in[6];
    const float* bf_ = (const float*)d_in[7];
    float* out = (float*)d_out;

    const int n  = in_sizes[0] / 256;
    const int ne = in_sizes[1] / 2;
    const int* srcp = ei;
    const int* dstp = ei + ne;
    const int B = (n + BK - 1) / BK;

    // ---- primary layout ----
    char* p = (char*)d_ws;
    u32*   ep     = (u32*)p;   p += (size_t)ne * 4;
    int*   bcnt   = (int*)p;   p += BPAD * 4;
    int*   boff   = (int*)p;   p += (BPAD + 1) * 4;
    int*   bcur   = (int*)p;   p += BPAD * 4;
    float* dinv   = (float*)p; p += (size_t)n * 4;
    int*   rowend = (int*)p;   p += (size_t)n * 4;
    float* gsum   = (float*)p; p += 64 * 4;
    int*   eidx   = (int*)p;   p += (size_t)ne * 4;
    float* parts  = (float*)p; p += (size_t)NBLK2 * 64 * 4;
    p = (char*)(((uintptr_t)p + 15) & ~(uintptr_t)15);
    u16*   wpack1 = (u16*)p;   p += 256 * 64 * 2;    // [8][4][64][8]
    u16*   wpack2 = (u16*)p;   p += 64 * 64 * 2;     // [2][4][64][8]
    u8*    hp     = (u8*)p;    p += (size_t)n * HID;
    u8*    h1     = (u8*)p;    p += (size_t)n * HID;
    size_t need = (size_t)(p - (char*)d_ws);

    if (ws_size >= need && n <= (1 << 17)) {
        (void)hipMemsetAsync(bcnt, 0, BPAD * 4, stream);
        (void)hipMemsetAsync(gsum, 0, 64 * 4, stream);
        hist_kernel<<<512, 256, 0, stream>>>(dstp, bcnt, ne, B);
        bucket_scan_kernel<<<1, 256, 0, stream>>>(bcnt, boff, bcur, B);
        partition_kernel<<<(ne + CH - 1) / CH, 256, 0, stream>>>(srcp, dstp, bcur, ep, ne);
        bucket_sort_kernel<<<B, 256, 0, stream>>>(ep, boff, eidx, rowend, dinv, n);
        pack_w_kernel<256><<<64, 256, 0, stream>>>(W1, wpack1);
        pack_w_kernel<64><<<16, 256, 0, stream>>>(W2, wpack2);

        const int ntiles = (n + 15) / 16;
        const int gblk = (ntiles + 3) / 4;
        mfma_gemm_kernel<256, float><<<gblk, 256, 0, stream>>>(x, wpack1, dinv, hp, n);
        agg_csr_kernel<<<(n + 3) / 4, 256, 0, stream>>>(hp, eidx, rowend, dinv, b1, h1, n);
        mfma_gemm_kernel<64, u8><<<gblk, 256, 0, stream>>>(h1, wpack2, dinv, hp, n);
        agg_csr_reduce_kernel<<<NBLK2, 256, 0, stream>>>(hp, eidx, rowend, dinv, b2, parts, n);
        gsum_stage_kernel<<<128, 256, 0, stream>>>(parts, NBLK2, gsum);
        final_gsum_kernel<<<1, 64, 0, stream>>>(gsum, Wf, bf_, out, 1.0f / (float)n);
    } else {
        // ---- fallback: atomic aggregation, fp8 hp, VALU gemm ----
        char* q = (char*)d_ws;
        float* dinvF = (float*)q; q += (size_t)n * 4;
        float* gsumF = (float*)q; q += 64 * 4;
        u8*    hpF   = (u8*)q;   q += (size_t)n * HID;
        float* aggF  = (float*)q;

        (void)hipMemsetAsync(dinvF, 0, ((size_t)n + 64) * 4, stream);
        deg_f_kernel<<<2048, 256, 0, stream>>>(dstp, dinvF, ne);
        dinvf_kernel<<<(n + 255) / 256, 256, 0, stream>>>(dinvF, n);

        gemm_scale_kernel<256, float><<<(n + 15) / 16, 256, 0, stream>>>(x, W1, dinvF, hpF, n);
        (void)hipMemsetAsync(aggF, 0, (size_t)n * HID * 4, stream);
        aggregate_atomic_kernel<<<(int)(((size_t)ne * 64 + 255) / 256), 256, 0, stream>>>(hpF, srcp, dstp, dinvF, aggF, ne);
        finalize1_fb_kernel<<<(int)(((size_t)n * HID + 255) / 256), 256, 0, stream>>>(hpF, aggF, dinvF, b1, n);

        gemm_scale_kernel<64, u8><<<(n + 15) / 16, 256, 0, stream>>>(hpF, W2, dinvF, hpF, n);
        (void)hipMemsetAsync(aggF, 0, (size_t)n * HID * 4, stream);
        aggregate_atomic_kernel<<<(int)(((size_t)ne * 64 + 255) / 256), 256, 0, stream>>>(hpF, srcp, dstp, dinvF, aggF, ne);
        finalize2_fb_kernel<<<2048, 256, 0, stream>>>(hpF, aggF, dinvF, b2, gsumF, n);
        final_gsum_fb_kernel<<<1, 64, 0, stream>>>(gsumF, Wf, bf_, out, n);
    }
}

// Round 10
// 301.180 us; speedup vs baseline: 9.6405x; 1.2118x over previous
//
#include <hip/hip_runtime.h>

// GCN: h1 = relu(gcnconv(x,W1,b1)); h2 = relu(gcnconv(h1,W2,b2));
// out = sigmoid(mean(h2,0) @ Wf + bf)
// hp = (x@W)*dinv[row] stored fp8 e4m3; aggregation = CSR gather (bucket-built),
// 4 edges per wave (4B/lane); GEMMs = MFMA 16x16x32 bf16 with prepacked W.

typedef unsigned int u32;
typedef unsigned short u16;
typedef unsigned char u8;
typedef short s16x8 __attribute__((ext_vector_type(8)));   // 8 bf16 bit-patterns
typedef __bf16 bf16x8 __attribute__((ext_vector_type(8))); // MFMA operand type
typedef float f32x4 __attribute__((ext_vector_type(4)));

constexpr int HID  = 64;
constexpr int SH   = 7;          // dst bucket shift
constexpr int BK   = 128;        // nodes per bucket
constexpr int BPAD = 1024;       // padded bucket count (needs n <= 131072)
constexpr int CH   = 4096;       // edges per partition block
constexpr int NBLK2 = 4096;      // blocks for fused layer-2 agg + reduce

static __device__ __forceinline__ u8 f2fp8(float f) {
    int p = __builtin_amdgcn_cvt_pk_fp8_f32(f, f, 0, false);
    return (u8)(p & 0xFF);
}
static __device__ __forceinline__ float fp82f(u8 v) {
    return __builtin_amdgcn_cvt_f32_fp8((int)v, 0);
}
static __device__ __forceinline__ u16 f2bf(float f) {
    u32 u = __float_as_uint(f);
    return (u16)((u + 0x7FFFu + ((u >> 16) & 1u)) >> 16);
}

// ---------- bucket histogram (LDS-privatized) ----------
__global__ __launch_bounds__(256) void hist_kernel(const int* __restrict__ dst,
                                                   int* __restrict__ bcnt, int ne, int B) {
    __shared__ int h[BPAD];
    for (int i = threadIdx.x; i < BPAD; i += 256) h[i] = 0;
    __syncthreads();
    int i = blockIdx.x * 256 + threadIdx.x, st = gridDim.x * 256;
    for (; i < ne; i += st) atomicAdd(&h[dst[i] >> SH], 1);
    __syncthreads();
    for (int b = threadIdx.x; b < B; b += 256) if (h[b]) atomicAdd(&bcnt[b], h[b]);
}

// ---------- exclusive scan of bucket counts (single block) ----------
__global__ __launch_bounds__(256) void bucket_scan_kernel(const int* __restrict__ bcnt,
                                                          int* __restrict__ boff,
                                                          int* __restrict__ bcur, int B) {
    __shared__ int ssc[256];
    int t = threadIdx.x, base = t * 4;
    int c[4];
    #pragma unroll
    for (int j = 0; j < 4; ++j) c[j] = (base + j < B) ? bcnt[base + j] : 0;
    int tsum = c[0] + c[1] + c[2] + c[3];
    ssc[t] = tsum; __syncthreads();
    int run = tsum;
    for (int off = 1; off < 256; off <<= 1) {
        int v = (t >= off) ? ssc[t - off] : 0;
        __syncthreads();
        run += v; ssc[t] = run;
        __syncthreads();
    }
    int ex = run - tsum;
    #pragma unroll
    for (int j = 0; j < 4; ++j) {
        int i = base + j;
        if (i <= B) { boff[i] = ex; if (i < B) bcur[i] = ex; }
        ex += c[j];
    }
}

// ---------- partition: emit packed (d7<<20|src) grouped by bucket ----------
__global__ __launch_bounds__(256) void partition_kernel(const int* __restrict__ src,
                                                        const int* __restrict__ dst,
                                                        int* __restrict__ bcur,
                                                        u32* __restrict__ ep, int ne) {
    __shared__ int hcnt[BPAD];
    __shared__ int hoff[BPAD];
    __shared__ int gbase[BPAD];
    __shared__ u32 stage[CH];
    __shared__ int ssc[256];
    const int t = threadIdx.x;
    const int base = blockIdx.x * CH;
    const int cnt = min(CH, ne - base);
    for (int i = t; i < BPAD; i += 256) hcnt[i] = 0;
    __syncthreads();

    int myr[CH / 256];
    #pragma unroll
    for (int k = 0; k < CH / 256; ++k) {
        int i = t + k * 256;
        if (i < cnt) myr[k] = atomicAdd(&hcnt[dst[base + i] >> SH], 1);
    }
    __syncthreads();
    {
        int c0 = hcnt[t*4], c1 = hcnt[t*4+1], c2 = hcnt[t*4+2], c3 = hcnt[t*4+3];
        int tsum = c0 + c1 + c2 + c3;
        ssc[t] = tsum; __syncthreads();
        int run = tsum;
        for (int off = 1; off < 256; off <<= 1) {
            int v = (t >= off) ? ssc[t - off] : 0;
            __syncthreads();
            run += v; ssc[t] = run;
            __syncthreads();
        }
        int ex = run - tsum;
        hoff[t*4] = ex; ex += c0;
        hoff[t*4+1] = ex; ex += c1;
        hoff[t*4+2] = ex; ex += c2;
        hoff[t*4+3] = ex;
    }
    __syncthreads();
    for (int b = t; b < BPAD; b += 256) {
        int c = hcnt[b];
        if (c) gbase[b] = atomicAdd(&bcur[b], c);
    }
    #pragma unroll
    for (int k = 0; k < CH / 256; ++k) {
        int i = t + k * 256;
        if (i < cnt) {
            int s = src[base + i], d = dst[base + i];
            stage[hoff[d >> SH] + myr[k]] = ((u32)(d & (BK - 1)) << 20) | (u32)s;
        }
    }
    __syncthreads();
    for (int i = t; i < cnt; i += 256) {
        u32 v = stage[i];
        int lo = 0;
        #pragma unroll
        for (int s = 512; s; s >>= 1) {
            int m = lo + s;
            if (m < BPAD && hoff[m] <= i) lo = m;
        }
        ep[gbase[lo] + (i - hoff[lo])] = v;
    }
}

// ---------- per-bucket counting sort -> eidx (src, dst-sorted), rowend, dinv ----------
__global__ __launch_bounds__(256) void bucket_sort_kernel(const u32* __restrict__ ep,
                                                          const int* __restrict__ boff,
                                                          int* __restrict__ eidx,
                                                          int* __restrict__ rowend,
                                                          float* __restrict__ dinv, int n) {
    __shared__ int cnt[BK];
    __shared__ int sc[BK];
    __shared__ int cur[BK];
    const int t = threadIdx.x, b = blockIdx.x;
    const int beg = boff[b], end = boff[b + 1];
    if (t < BK) cnt[t] = 0;
    __syncthreads();
    for (int p = beg + t; p < end; p += 256) atomicAdd(&cnt[ep[p] >> 20], 1);
    __syncthreads();
    if (t < BK) sc[t] = cnt[t];
    __syncthreads();
    for (int o = 1; o < BK; o <<= 1) {
        int v = 0;
        if (t < BK && t >= o) v = sc[t - o];
        __syncthreads();
        if (t < BK) sc[t] += v;
        __syncthreads();
    }
    if (t < BK) {
        int node = b * BK + t;
        if (node < n) {
            rowend[node] = beg + sc[t];
            dinv[node] = rsqrtf((float)cnt[t] + 1.0f);
        }
        cur[t] = beg + sc[t] - cnt[t];
    }
    __syncthreads();
    for (int p = beg + t; p < end; p += 256) {
        u32 v = ep[p];
        int r = atomicAdd(&cur[v >> 20], 1);
        eidx[r] = (int)(v & 0xFFFFFu);
    }
}

// ---------- W pack: wpack[kk][nt][lane][i] = bf16 W[kk*32+(lane>>4)*8+i][nt*16+(lane&15)] ----------
template <int K>
__global__ void pack_w_kernel(const float* __restrict__ W, u16* __restrict__ wpack) {
    int i = blockIdx.x * 256 + threadIdx.x;
    if (i >= K * 64) return;
    int e = i & 7, lane = (i >> 3) & 63, nt = (i >> 9) & 3, kk = i >> 11;
    int k = kk * 32 + (lane >> 4) * 8 + e;
    int c = nt * 16 + (lane & 15);
    wpack[i] = f2bf(W[k * HID + c]);
}

// ---------- MFMA GEMM: out8[r][c] = fp8( (A[r,:]@W[:,c]) * dinv[r] ) ----------
template <int K, typename TIn>
__global__ __launch_bounds__(256) void mfma_gemm_kernel(const TIn* __restrict__ A,
                                                        const u16* __restrict__ wpack,
                                                        const float* __restrict__ dinv,
                                                        u8* __restrict__ out8, int n) {
    const int t = threadIdx.x;
    const int lane = t & 63;
    const int wid = t >> 6;
    const int r16 = lane & 15;
    const int kgrp = lane >> 4;
    const int ntiles = (n + 15) >> 4;
    for (int tile = blockIdx.x * 4 + wid; tile < ntiles; tile += gridDim.x * 4) {
        const int row0 = tile * 16;
        const int arow = row0 + r16;
        f32x4 acc[4] = {f32x4{0,0,0,0}, f32x4{0,0,0,0}, f32x4{0,0,0,0}, f32x4{0,0,0,0}};
        #pragma unroll
        for (int kk = 0; kk < K / 32; ++kk) {
            s16x8 abits;
            if constexpr (sizeof(TIn) == 4) {
                const float* Af = (const float*)A;
                if (arow < n) {
                    const float4* p0 = (const float4*)(Af + (size_t)arow * K + kk * 32 + kgrp * 8);
                    float4 v0 = p0[0], v1 = p0[1];
                    abits[0] = (short)f2bf(v0.x); abits[1] = (short)f2bf(v0.y);
                    abits[2] = (short)f2bf(v0.z); abits[3] = (short)f2bf(v0.w);
                    abits[4] = (short)f2bf(v1.x); abits[5] = (short)f2bf(v1.y);
                    abits[6] = (short)f2bf(v1.z); abits[7] = (short)f2bf(v1.w);
                } else {
                    #pragma unroll
                    for (int j = 0; j < 8; ++j) abits[j] = 0;
                }
            } else {
                const u8* Ab = (const u8*)A;
                u32 w0 = 0, w1 = 0;
                if (arow < n) {
                    const u32* p0 = (const u32*)(Ab + (size_t)arow * K + kk * 32 + kgrp * 8);
                    w0 = p0[0]; w1 = p0[1];
                }
                abits[0] = (short)f2bf(__builtin_amdgcn_cvt_f32_fp8((int)w0, 0));
                abits[1] = (short)f2bf(__builtin_amdgcn_cvt_f32_fp8((int)w0, 1));
                abits[2] = (short)f2bf(__builtin_amdgcn_cvt_f32_fp8((int)w0, 2));
                abits[3] = (short)f2bf(__builtin_amdgcn_cvt_f32_fp8((int)w0, 3));
                abits[4] = (short)f2bf(__builtin_amdgcn_cvt_f32_fp8((int)w1, 0));
                abits[5] = (short)f2bf(__builtin_amdgcn_cvt_f32_fp8((int)w1, 1));
                abits[6] = (short)f2bf(__builtin_amdgcn_cvt_f32_fp8((int)w1, 2));
                abits[7] = (short)f2bf(__builtin_amdgcn_cvt_f32_fp8((int)w1, 3));
            }
            bf16x8 afrag = __builtin_bit_cast(bf16x8, abits);
            const u16* wp = wpack + ((size_t)(kk * 4) * 64 + lane) * 8;
            #pragma unroll
            for (int nt = 0; nt < 4; ++nt) {
                bf16x8 bfrag = *(const bf16x8*)(wp + (size_t)nt * 64 * 8);
                acc[nt] = __builtin_amdgcn_mfma_f32_16x16x32_bf16(afrag, bfrag, acc[nt], 0, 0, 0);
            }
        }
        #pragma unroll
        for (int reg = 0; reg < 4; ++reg) {
            int r = row0 + kgrp * 4 + reg;
            if (r < n) {
                float dv = dinv[r];
                #pragma unroll
                for (int nt = 0; nt < 4; ++nt)
                    out8[(size_t)r * HID + nt * 16 + r16] = f2fp8(acc[nt][reg] * dv);
            }
        }
    }
}

// ---------- CSR gather aggregation, 4 edges/wave (4B per lane) ----------
// lane: g = lane>>4 (edge slot), fb = lane&15 (feature block of 4)
__global__ __launch_bounds__(256) void agg_csr_kernel(const u8* __restrict__ hp,
                                                      const int* __restrict__ eidx,
                                                      const int* __restrict__ rowend,
                                                      const float* __restrict__ dinv,
                                                      const float* __restrict__ bias,
                                                      u8* __restrict__ out, int n) {
    int w = (blockIdx.x * 256 + threadIdx.x) >> 6;
    int lane = threadIdx.x & 63;
    if (w >= n) return;
    const int g = lane >> 4, fb = lane & 15;
    int beg = w ? rowend[w - 1] : 0;
    int end = rowend[w];
    float a0 = 0.f, a1 = 0.f, a2 = 0.f, a3 = 0.f;
    int p = beg;
    for (; p + 16 <= end; p += 16) {
        int s0 = __builtin_nontemporal_load(eidx + p + g);
        int s1 = __builtin_nontemporal_load(eidx + p + 4 + g);
        int s2 = __builtin_nontemporal_load(eidx + p + 8 + g);
        int s3 = __builtin_nontemporal_load(eidx + p + 12 + g);
        u32 w0 = *(const u32*)(hp + (size_t)s0 * 64 + fb * 4);
        u32 w1 = *(const u32*)(hp + (size_t)s1 * 64 + fb * 4);
        u32 w2 = *(const u32*)(hp + (size_t)s2 * 64 + fb * 4);
        u32 w3 = *(const u32*)(hp + (size_t)s3 * 64 + fb * 4);
        a0 += __builtin_amdgcn_cvt_f32_fp8((int)w0, 0) + __builtin_amdgcn_cvt_f32_fp8((int)w1, 0)
            + __builtin_amdgcn_cvt_f32_fp8((int)w2, 0) + __builtin_amdgcn_cvt_f32_fp8((int)w3, 0);
        a1 += __builtin_amdgcn_cvt_f32_fp8((int)w0, 1) + __builtin_amdgcn_cvt_f32_fp8((int)w1, 1)
            + __builtin_amdgcn_cvt_f32_fp8((int)w2, 1) + __builtin_amdgcn_cvt_f32_fp8((int)w3, 1);
        a2 += __builtin_amdgcn_cvt_f32_fp8((int)w0, 2) + __builtin_amdgcn_cvt_f32_fp8((int)w1, 2)
            + __builtin_amdgcn_cvt_f32_fp8((int)w2, 2) + __builtin_amdgcn_cvt_f32_fp8((int)w3, 2);
        a3 += __builtin_amdgcn_cvt_f32_fp8((int)w0, 3) + __builtin_amdgcn_cvt_f32_fp8((int)w1, 3)
            + __builtin_amdgcn_cvt_f32_fp8((int)w2, 3) + __builtin_amdgcn_cvt_f32_fp8((int)w3, 3);
    }
    for (; p < end; p += 4) {
        int idx = p + g;
        bool valid = idx < end;
        int s = __builtin_nontemporal_load(eidx + (valid ? idx : beg));
        u32 wv = *(const u32*)(hp + (size_t)s * 64 + fb * 4);
        if (valid) {
            a0 += __builtin_amdgcn_cvt_f32_fp8((int)wv, 0);
            a1 += __builtin_amdgcn_cvt_f32_fp8((int)wv, 1);
            a2 += __builtin_amdgcn_cvt_f32_fp8((int)wv, 2);
            a3 += __builtin_amdgcn_cvt_f32_fp8((int)wv, 3);
        }
    }
    // reduce across the 4 edge-slot groups (same fb)
    a0 += __shfl_xor(a0, 16); a0 += __shfl_xor(a0, 32);
    a1 += __shfl_xor(a1, 16); a1 += __shfl_xor(a1, 32);
    a2 += __shfl_xor(a2, 16); a2 += __shfl_xor(a2, 32);
    a3 += __shfl_xor(a3, 16); a3 += __shfl_xor(a3, 32);
    // self term + bias + relu, pack 4 fp8
    u32 sv = *(const u32*)(hp + (size_t)w * 64 + fb * 4);
    float dv = dinv[w];
    float v0 = fmaxf(dv * (a0 + __builtin_amdgcn_cvt_f32_fp8((int)sv, 0)) + bias[fb * 4 + 0], 0.f);
    float v1 = fmaxf(dv * (a1 + __builtin_amdgcn_cvt_f32_fp8((int)sv, 1)) + bias[fb * 4 + 1], 0.f);
    float v2 = fmaxf(dv * (a2 + __builtin_amdgcn_cvt_f32_fp8((int)sv, 2)) + bias[fb * 4 + 2], 0.f);
    float v3 = fmaxf(dv * (a3 + __builtin_amdgcn_cvt_f32_fp8((int)sv, 3)) + bias[fb * 4 + 3], 0.f);
    if (g == 0) {
        int r = __builtin_amdgcn_cvt_pk_fp8_f32(v0, v1, 0, false);
        r = __builtin_amdgcn_cvt_pk_fp8_f32(v2, v3, r, true);
        *(u32*)(out + (size_t)w * 64 + fb * 4) = (u32)r;
    }
}

// ---------- layer 2: 4-edge/wave CSR aggregation fused with graph-mean partials ----------
__global__ __launch_bounds__(256) void agg_csr_reduce_kernel(const u8* __restrict__ hp,
                                                             const int* __restrict__ eidx,
                                                             const int* __restrict__ rowend,
                                                             const float* __restrict__ dinv,
                                                             const float* __restrict__ bias,
                                                             float* __restrict__ partials, int n) {
    __shared__ float sred[256];
    int t = threadIdx.x, lane = t & 63;
    const int g = lane >> 4, fb = lane & 15;
    int wid = (blockIdx.x * 256 + t) >> 6;
    int wstride = gridDim.x * 4;
    float bl0 = bias[fb * 4 + 0], bl1 = bias[fb * 4 + 1];
    float bl2 = bias[fb * 4 + 2], bl3 = bias[fb * 4 + 3];
    float t0 = 0.f, t1 = 0.f, t2 = 0.f, t3 = 0.f;
    for (int w = wid; w < n; w += wstride) {
        int beg = w ? rowend[w - 1] : 0;
        int end = rowend[w];
        float a0 = 0.f, a1 = 0.f, a2 = 0.f, a3 = 0.f;
        int p = beg;
        for (; p + 16 <= end; p += 16) {
            int s0 = __builtin_nontemporal_load(eidx + p + g);
            int s1 = __builtin_nontemporal_load(eidx + p + 4 + g);
            int s2 = __builtin_nontemporal_load(eidx + p + 8 + g);
            int s3 = __builtin_nontemporal_load(eidx + p + 12 + g);
            u32 w0 = *(const u32*)(hp + (size_t)s0 * 64 + fb * 4);
            u32 w1 = *(const u32*)(hp + (size_t)s1 * 64 + fb * 4);
            u32 w2 = *(const u32*)(hp + (size_t)s2 * 64 + fb * 4);
            u32 w3 = *(const u32*)(hp + (size_t)s3 * 64 + fb * 4);
            a0 += __builtin_amdgcn_cvt_f32_fp8((int)w0, 0) + __builtin_amdgcn_cvt_f32_fp8((int)w1, 0)
                + __builtin_amdgcn_cvt_f32_fp8((int)w2, 0) + __builtin_amdgcn_cvt_f32_fp8((int)w3, 0);
            a1 += __builtin_amdgcn_cvt_f32_fp8((int)w0, 1) + __builtin_amdgcn_cvt_f32_fp8((int)w1, 1)
                + __builtin_amdgcn_cvt_f32_fp8((int)w2, 1) + __builtin_amdgcn_cvt_f32_fp8((int)w3, 1);
            a2 += __builtin_amdgcn_cvt_f32_fp8((int)w0, 2) + __builtin_amdgcn_cvt_f32_fp8((int)w1, 2)
                + __builtin_amdgcn_cvt_f32_fp8((int)w2, 2) + __builtin_amdgcn_cvt_f32_fp8((int)w3, 2);
            a3 += __builtin_amdgcn_cvt_f32_fp8((int)w0, 3) + __builtin_amdgcn_cvt_f32_fp8((int)w1, 3)
                + __builtin_amdgcn_cvt_f32_fp8((int)w2, 3) + __builtin_amdgcn_cvt_f32_fp8((int)w3, 3);
        }
        for (; p < end; p += 4) {
            int idx = p + g;
            bool valid = idx < end;
            int s = __builtin_nontemporal_load(eidx + (valid ? idx : beg));
            u32 wv = *(const u32*)(hp + (size_t)s * 64 + fb * 4);
            if (valid) {
                a0 += __builtin_amdgcn_cvt_f32_fp8((int)wv, 0);
                a1 += __builtin_amdgcn_cvt_f32_fp8((int)wv, 1);
                a2 += __builtin_amdgcn_cvt_f32_fp8((int)wv, 2);
                a3 += __builtin_amdgcn_cvt_f32_fp8((int)wv, 3);
            }
        }
        a0 += __shfl_xor(a0, 16); a0 += __shfl_xor(a0, 32);
        a1 += __shfl_xor(a1, 16); a1 += __shfl_xor(a1, 32);
        a2 += __shfl_xor(a2, 16); a2 += __shfl_xor(a2, 32);
        a3 += __shfl_xor(a3, 16); a3 += __shfl_xor(a3, 32);
        u32 sv = *(const u32*)(hp + (size_t)w * 64 + fb * 4);
        float dv = dinv[w];
        t0 += fmaxf(dv * (a0 + __builtin_amdgcn_cvt_f32_fp8((int)sv, 0)) + bl0, 0.f);
        t1 += fmaxf(dv * (a1 + __builtin_amdgcn_cvt_f32_fp8((int)sv, 1)) + bl1, 0.f);
        t2 += fmaxf(dv * (a2 + __builtin_amdgcn_cvt_f32_fp8((int)sv, 2)) + bl2, 0.f);
        t3 += fmaxf(dv * (a3 + __builtin_amdgcn_cvt_f32_fp8((int)sv, 3)) + bl3, 0.f);
    }
    int wv_ = t >> 6;
    if (g == 0) {
        sred[wv_ * 64 + fb * 4 + 0] = t0;
        sred[wv_ * 64 + fb * 4 + 1] = t1;
        sred[wv_ * 64 + fb * 4 + 2] = t2;
        sred[wv_ * 64 + fb * 4 + 3] = t3;
    }
    __syncthreads();
    if (t < 64) partials[blockIdx.x * 64 + t] = sred[t] + sred[t + 64] + sred[t + 128] + sred[t + 192];
}

// ---------- two-stage partial reduction ----------
__global__ __launch_bounds__(256) void gsum_stage_kernel(const float* __restrict__ parts, int nblk,
                                                         float* __restrict__ gsum) {
    __shared__ float sred[256];
    int t = threadIdx.x, col = t & 63;
    float a = 0.f;
    for (int bk = blockIdx.x * 4 + (t >> 6); bk < nblk; bk += gridDim.x * 4)
        a += parts[bk * 64 + col];
    sred[t] = a; __syncthreads();
    if (t < 64) atomicAdd(&gsum[t], sred[t] + sred[t + 64] + sred[t + 128] + sred[t + 192]);
}

__global__ void final_gsum_kernel(const float* __restrict__ gsum, const float* __restrict__ Wf,
                                  const float* __restrict__ bf_, float* __restrict__ out, float invn) {
    int lane = threadIdx.x;
    float v = gsum[lane] * invn * Wf[lane];
    #pragma unroll
    for (int off = 32; off; off >>= 1) v += __shfl_down(v, off);
    if (lane == 0) out[0] = 1.f / (1.f + expf(-(v + bf_[0])));
}

// ================= fallback (atomic aggregation, fp8 hp, VALU gemm) =================
template <int K, typename TIn>
__global__ __launch_bounds__(256) void gemm_scale_kernel(const TIn* __restrict__ A,
                                                         const float* __restrict__ W,
                                                         const float* __restrict__ dinv,
                                                         u8* __restrict__ out8, int n) {
    __shared__ float xs[16][K];
    const int t = threadIdx.x;
    const int row0 = blockIdx.x * 16;
    if constexpr (sizeof(TIn) == 4) {
        const float* Af = (const float*)A;
        for (int i = t; i < 16 * K; i += 256) {
            int r = i / K;
            (&xs[0][0])[i] = (row0 + r < n) ? Af[(size_t)row0 * K + i] : 0.f;
        }
    } else {
        const u8* Ab = (const u8*)A;
        for (int i = t; i < 16 * K; i += 256) {
            int r = i / K;
            (&xs[0][0])[i] = (row0 + r < n) ? fp82f(Ab[(size_t)row0 * K + i]) : 0.f;
        }
    }
    __syncthreads();
    const int c = t & 63, rg = t >> 6;
    float acc[4] = {0.f, 0.f, 0.f, 0.f};
    #pragma unroll 4
    for (int k = 0; k < K; ++k) {
        float w = W[k * HID + c];
        #pragma unroll
        for (int j = 0; j < 4; ++j) acc[j] += xs[rg + 4 * j][k] * w;
    }
    #pragma unroll
    for (int j = 0; j < 4; ++j) {
        int r = row0 + rg + 4 * j;
        if (r < n) out8[(size_t)r * HID + c] = f2fp8(acc[j] * dinv[r]);
    }
}
__global__ void deg_f_kernel(const int* __restrict__ dst, float* __restrict__ deg, int ne) {
    int i = blockIdx.x * blockDim.x + threadIdx.x, st = gridDim.x * blockDim.x;
    for (; i < ne; i += st) atomicAdd(&deg[dst[i]], 1.0f);
}
__global__ void dinvf_kernel(float* __restrict__ deg, int n) {
    int i = blockIdx.x * blockDim.x + threadIdx.x;
    if (i < n) deg[i] = rsqrtf(deg[i] + 1.0f);
}
__global__ __launch_bounds__(256) void aggregate_atomic_kernel(const u8* __restrict__ hp,
        const int* __restrict__ src, const int* __restrict__ dst,
        const float* __restrict__ dinv, float* __restrict__ outf, int ne) {
    size_t tt = (size_t)blockIdx.x * 256 + threadIdx.x;
    int e = (int)(tt >> 6), f = (int)(tt & 63);
    if (e >= ne) return;
    int s = src[e], d = dst[e];
    atomicAdd(&outf[(size_t)d * HID + f], fp82f(hp[s * HID + f]) * dinv[d]);
}
__global__ void finalize1_fb_kernel(u8* __restrict__ hp, const float* __restrict__ agg,
                                    const float* __restrict__ dinv, const float* __restrict__ b, int n) {
    size_t i = (size_t)blockIdx.x * blockDim.x + threadIdx.x;
    if (i >= (size_t)n * HID) return;
    int node = (int)(i >> 6);
    float v = agg[i] + fp82f(hp[i]) * dinv[node] + b[i & 63];
    hp[i] = f2fp8(fmaxf(v, 0.f));
}
__global__ __launch_bounds__(256) void finalize2_fb_kernel(const u8* __restrict__ hp,
        const float* __restrict__ agg, const float* __restrict__ dinv,
        const float* __restrict__ b, float* __restrict__ gsum, int n) {
    __shared__ float sred[256];
    const int t = threadIdx.x, c = t & 63;
    const size_t total = (size_t)n * HID;
    const size_t stride = (size_t)gridDim.x * blockDim.x;
    float acc = 0.f;
    for (size_t i = (size_t)blockIdx.x * blockDim.x + t; i < total; i += stride) {
        int node = (int)(i >> 6);
        acc += fmaxf(agg[i] + fp82f(hp[i]) * dinv[node] + b[c], 0.f);
    }
    sred[t] = acc; __syncthreads();
    if (t < 64) atomicAdd(&gsum[c], sred[t] + sred[t + 64] + sred[t + 128] + sred[t + 192]);
}
__global__ void final_gsum_fb_kernel(const float* __restrict__ gsum, const float* __restrict__ Wf,
                                     const float* __restrict__ bf_, float* __restrict__ out, int n) {
    int lane = threadIdx.x;
    float v = (gsum[lane] / (float)n) * Wf[lane];
    #pragma unroll
    for (int off = 32; off; off >>= 1) v += __shfl_down(v, off);
    if (lane == 0) out[0] = 1.f / (1.f + expf(-(v + bf_[0])));
}

extern "C" void kernel_launch(void* const* d_in, const int* in_sizes, int n_in,
                              void* d_out, int out_size, void* d_ws, size_t ws_size,
                              hipStream_t stream) {
    const float* x  = (const float*)d_in[0];
    const int*   ei = (const int*)d_in[1];
    const float* W1 = (const float*)d_in[2];
    const float* b1 = (const float*)d_in[3];
    const float* W2 = (const float*)d_in[4];
    const float* b2 = (const float*)d_in[5];
    const float* Wf = (const float*)d_in[6];
    const float* bf_ = (const float*)d_in[7];
    float* out = (float*)d_out;

    const int n  = in_sizes[0] / 256;
    const int ne = in_sizes[1] / 2;
    const int* srcp = ei;
    const int* dstp = ei + ne;
    const int B = (n + BK - 1) / BK;

    // ---- primary layout ----
    char* p = (char*)d_ws;
    u32*   ep     = (u32*)p;   p += (size_t)ne * 4;
    int*   bcnt   = (int*)p;   p += BPAD * 4;
    int*   boff   = (int*)p;   p += (BPAD + 1) * 4;
    int*   bcur   = (int*)p;   p += BPAD * 4;
    float* dinv   = (float*)p; p += (size_t)n * 4;
    int*   rowend = (int*)p;   p += (size_t)n * 4;
    float* gsum   = (float*)p; p += 64 * 4;
    int*   eidx   = (int*)p;   p += (size_t)ne * 4;
    float* parts  = (float*)p; p += (size_t)NBLK2 * 64 * 4;
    p = (char*)(((uintptr_t)p + 15) & ~(uintptr_t)15);
    u16*   wpack1 = (u16*)p;   p += 256 * 64 * 2;    // [8][4][64][8]
    u16*   wpack2 = (u16*)p;   p += 64 * 64 * 2;     // [2][4][64][8]
    u8*    hp     = (u8*)p;    p += (size_t)n * HID;
    u8*    h1     = (u8*)p;    p += (size_t)n * HID;
    size_t need = (size_t)(p - (char*)d_ws);

    if (ws_size >= need && n <= (1 << 17)) {
        (void)hipMemsetAsync(bcnt, 0, BPAD * 4, stream);
        (void)hipMemsetAsync(gsum, 0, 64 * 4, stream);
        hist_kernel<<<512, 256, 0, stream>>>(dstp, bcnt, ne, B);
        bucket_scan_kernel<<<1, 256, 0, stream>>>(bcnt, boff, bcur, B);
        partition_kernel<<<(ne + CH - 1) / CH, 256, 0, stream>>>(srcp, dstp, bcur, ep, ne);
        bucket_sort_kernel<<<B, 256, 0, stream>>>(ep, boff, eidx, rowend, dinv, n);
        pack_w_kernel<256><<<64, 256, 0, stream>>>(W1, wpack1);
        pack_w_kernel<64><<<16, 256, 0, stream>>>(W2, wpack2);

        const int ntiles = (n + 15) / 16;
        const int gblk = (ntiles + 3) / 4;
        mfma_gemm_kernel<256, float><<<gblk, 256, 0, stream>>>(x, wpack1, dinv, hp, n);
        agg_csr_kernel<<<(n + 3) / 4, 256, 0, stream>>>(hp, eidx, rowend, dinv, b1, h1, n);
        mfma_gemm_kernel<64, u8><<<gblk, 256, 0, stream>>>(h1, wpack2, dinv, hp, n);
        agg_csr_reduce_kernel<<<NBLK2, 256, 0, stream>>>(hp, eidx, rowend, dinv, b2, parts, n);
        gsum_stage_kernel<<<128, 256, 0, stream>>>(parts, NBLK2, gsum);
        final_gsum_kernel<<<1, 64, 0, stream>>>(gsum, Wf, bf_, out, 1.0f / (float)n);
    } else {
        // ---- fallback: atomic aggregation, fp8 hp, VALU gemm ----
        char* q = (char*)d_ws;
        float* dinvF = (float*)q; q += (size_t)n * 4;
        float* gsumF = (float*)q; q += 64 * 4;
        u8*    hpF   = (u8*)q;   q += (size_t)n * HID;
        float* aggF  = (float*)q;

        (void)hipMemsetAsync(dinvF, 0, ((size_t)n + 64) * 4, stream);
        deg_f_kernel<<<2048, 256, 0, stream>>>(dstp, dinvF, ne);
        dinvf_kernel<<<(n + 255) / 256, 256, 0, stream>>>(dinvF, n);

        gemm_scale_kernel<256, float><<<(n + 15) / 16, 256, 0, stream>>>(x, W1, dinvF, hpF, n);
        (void)hipMemsetAsync(aggF, 0, (size_t)n * HID * 4, stream);
        aggregate_atomic_kernel<<<(int)(((size_t)ne * 64 + 255) / 256), 256, 0, stream>>>(hpF, srcp, dstp, dinvF, aggF, ne);
        finalize1_fb_kernel<<<(int)(((size_t)n * HID + 255) / 256), 256, 0, stream>>>(hpF, aggF, dinvF, b1, n);

        gemm_scale_kernel<64, u8><<<(n + 15) / 16, 256, 0, stream>>>(hpF, W2, dinvF, hpF, n);
        (void)hipMemsetAsync(aggF, 0, (size_t)n * HID * 4, stream);
        aggregate_atomic_kernel<<<(int)(((size_t)ne * 64 + 255) / 256), 256, 0, stream>>>(hpF, srcp, dstp, dinvF, aggF, ne);
        finalize2_fb_kernel<<<2048, 256, 0, stream>>>(hpF, aggF, dinvF, b2, gsumF, n);
        final_gsum_fb_kernel<<<1, 64, 0, stream>>>(gsumF, Wf, bf_, out, n);
    }
}

// Round 11
// 267.927 us; speedup vs baseline: 10.8369x; 1.1241x over previous
//
#include <hip/hip_runtime.h>

// GCN: h1 = relu(gcnconv(x,W1,b1)); h2 = relu(gcnconv(h1,W2,b2));
// out = sigmoid(mean(h2,0) @ Wf + bf)
// hp = (x@W)*dinv[row] stored fp8 e4m3; aggregation = CSR gather (bucket-built),
// 4 edges per wave (4B/lane), 32-edge unrolled; GEMMs = MFMA 16x16x32 bf16.
// CSR: fixed-slack bucket slots (no hist/scan) + per-bucket counting sort.

typedef unsigned int u32;
typedef unsigned short u16;
typedef unsigned char u8;
typedef short s16x8 __attribute__((ext_vector_type(8)));   // 8 bf16 bit-patterns
typedef __bf16 bf16x8 __attribute__((ext_vector_type(8))); // MFMA operand type
typedef float f32x4 __attribute__((ext_vector_type(4)));

constexpr int HID  = 64;
constexpr int SH   = 7;          // dst bucket shift
constexpr int BK   = 128;        // nodes per bucket
constexpr int BPAD = 1024;       // padded bucket count (needs n <= 131072)
constexpr int CH   = 4096;       // edges per partition block
constexpr int SLOT = 5120;       // edge slots per bucket (mean 4096 + 16 sigma)
constexpr int NBLK2 = 4096;      // blocks for fused layer-2 agg + reduce

static __device__ __forceinline__ u8 f2fp8(float f) {
    int p = __builtin_amdgcn_cvt_pk_fp8_f32(f, f, 0, false);
    return (u8)(p & 0xFF);
}
static __device__ __forceinline__ float fp82f(u8 v) {
    return __builtin_amdgcn_cvt_f32_fp8((int)v, 0);
}
static __device__ __forceinline__ u16 f2bf(float f) {
    u32 u = __float_as_uint(f);
    return (u16)((u + 0x7FFFu + ((u >> 16) & 1u)) >> 16);
}

// ---------- init bucket cursors: bcur[b] = b*SLOT ----------
__global__ void init_bcur_kernel(int* __restrict__ bcur, int B) {
    int b = blockIdx.x * 256 + threadIdx.x;
    if (b < B) bcur[b] = b * SLOT;
}

// ---------- partition: emit packed (d7<<20|src) into fixed bucket slots ----------
__global__ __launch_bounds__(256) void partition_kernel(const int* __restrict__ src,
                                                        const int* __restrict__ dst,
                                                        int* __restrict__ bcur,
                                                        u32* __restrict__ ep, int ne) {
    __shared__ int hcnt[BPAD];
    __shared__ int hoff[BPAD];
    __shared__ int gbase[BPAD];
    __shared__ u32 stage[CH];
    __shared__ int ssc[256];
    const int t = threadIdx.x;
    const int base = blockIdx.x * CH;
    const int cnt = min(CH, ne - base);
    for (int i = t; i < BPAD; i += 256) hcnt[i] = 0;
    __syncthreads();

    int myr[CH / 256];
    #pragma unroll
    for (int k = 0; k < CH / 256; ++k) {
        int i = t + k * 256;
        if (i < cnt) myr[k] = atomicAdd(&hcnt[dst[base + i] >> SH], 1);
    }
    __syncthreads();
    {
        int c0 = hcnt[t*4], c1 = hcnt[t*4+1], c2 = hcnt[t*4+2], c3 = hcnt[t*4+3];
        int tsum = c0 + c1 + c2 + c3;
        ssc[t] = tsum; __syncthreads();
        int run = tsum;
        for (int off = 1; off < 256; off <<= 1) {
            int v = (t >= off) ? ssc[t - off] : 0;
            __syncthreads();
            run += v; ssc[t] = run;
            __syncthreads();
        }
        int ex = run - tsum;
        hoff[t*4] = ex; ex += c0;
        hoff[t*4+1] = ex; ex += c1;
        hoff[t*4+2] = ex; ex += c2;
        hoff[t*4+3] = ex;
    }
    __syncthreads();
    for (int b = t; b < BPAD; b += 256) {
        int c = hcnt[b];
        if (c) gbase[b] = atomicAdd(&bcur[b], c);
    }
    #pragma unroll
    for (int k = 0; k < CH / 256; ++k) {
        int i = t + k * 256;
        if (i < cnt) {
            int s = src[base + i], d = dst[base + i];
            stage[hoff[d >> SH] + myr[k]] = ((u32)(d & (BK - 1)) << 20) | (u32)s;
        }
    }
    __syncthreads();
    for (int i = t; i < cnt; i += 256) {
        u32 v = stage[i];
        int lo = 0;
        #pragma unroll
        for (int s = 512; s; s >>= 1) {
            int m = lo + s;
            if (m < BPAD && hoff[m] <= i) lo = m;
        }
        ep[gbase[lo] + (i - hoff[lo])] = v;
    }
}

// ---------- per-bucket counting sort -> eidx (src, dst-sorted), rowend, dinv ----------
__global__ __launch_bounds__(256) void bucket_sort_kernel(const u32* __restrict__ ep,
                                                          const int* __restrict__ bcur,
                                                          int* __restrict__ eidx,
                                                          int* __restrict__ rowend,
                                                          float* __restrict__ dinv, int n) {
    __shared__ int cnt[BK];
    __shared__ int sc[BK];
    __shared__ int cur[BK];
    const int t = threadIdx.x, b = blockIdx.x;
    const int beg = b * SLOT, end = bcur[b];
    if (t < BK) cnt[t] = 0;
    __syncthreads();
    for (int p = beg + t; p < end; p += 256) atomicAdd(&cnt[ep[p] >> 20], 1);
    __syncthreads();
    if (t < BK) sc[t] = cnt[t];
    __syncthreads();
    for (int o = 1; o < BK; o <<= 1) {
        int v = 0;
        if (t < BK && t >= o) v = sc[t - o];
        __syncthreads();
        if (t < BK) sc[t] += v;
        __syncthreads();
    }
    if (t < BK) {
        int node = b * BK + t;
        if (node < n) {
            rowend[node] = beg + sc[t];
            dinv[node] = rsqrtf((float)cnt[t] + 1.0f);
        }
        cur[t] = beg + sc[t] - cnt[t];
    }
    __syncthreads();
    for (int p = beg + t; p < end; p += 256) {
        u32 v = ep[p];
        int r = atomicAdd(&cur[v >> 20], 1);
        eidx[r] = (int)(v & 0xFFFFFu);
    }
}

// ---------- W pack: wpack[kk][nt][lane][i] = bf16 W[kk*32+(lane>>4)*8+i][nt*16+(lane&15)] ----------
template <int K>
__global__ void pack_w_kernel(const float* __restrict__ W, u16* __restrict__ wpack) {
    int i = blockIdx.x * 256 + threadIdx.x;
    if (i >= K * 64) return;
    int e = i & 7, lane = (i >> 3) & 63, nt = (i >> 9) & 3, kk = i >> 11;
    int k = kk * 32 + (lane >> 4) * 8 + e;
    int c = nt * 16 + (lane & 15);
    wpack[i] = f2bf(W[k * HID + c]);
}

// ---------- MFMA GEMM: out8[r][c] = fp8( (A[r,:]@W[:,c]) * dinv[r] ) ----------
template <int K, typename TIn>
__global__ __launch_bounds__(256) void mfma_gemm_kernel(const TIn* __restrict__ A,
                                                        const u16* __restrict__ wpack,
                                                        const float* __restrict__ dinv,
                                                        u8* __restrict__ out8, int n) {
    const int t = threadIdx.x;
    const int lane = t & 63;
    const int wid = t >> 6;
    const int r16 = lane & 15;
    const int kgrp = lane >> 4;
    const int ntiles = (n + 15) >> 4;
    for (int tile = blockIdx.x * 4 + wid; tile < ntiles; tile += gridDim.x * 4) {
        const int row0 = tile * 16;
        const int arow = row0 + r16;
        f32x4 acc[4] = {f32x4{0,0,0,0}, f32x4{0,0,0,0}, f32x4{0,0,0,0}, f32x4{0,0,0,0}};
        #pragma unroll
        for (int kk = 0; kk < K / 32; ++kk) {
            s16x8 abits;
            if constexpr (sizeof(TIn) == 4) {
                const float* Af = (const float*)A;
                if (arow < n) {
                    const float4* p0 = (const float4*)(Af + (size_t)arow * K + kk * 32 + kgrp * 8);
                    float4 v0 = p0[0], v1 = p0[1];
                    abits[0] = (short)f2bf(v0.x); abits[1] = (short)f2bf(v0.y);
                    abits[2] = (short)f2bf(v0.z); abits[3] = (short)f2bf(v0.w);
                    abits[4] = (short)f2bf(v1.x); abits[5] = (short)f2bf(v1.y);
                    abits[6] = (short)f2bf(v1.z); abits[7] = (short)f2bf(v1.w);
                } else {
                    #pragma unroll
                    for (int j = 0; j < 8; ++j) abits[j] = 0;
                }
            } else {
                const u8* Ab = (const u8*)A;
                u32 w0 = 0, w1 = 0;
                if (arow < n) {
                    const u32* p0 = (const u32*)(Ab + (size_t)arow * K + kk * 32 + kgrp * 8);
                    w0 = p0[0]; w1 = p0[1];
                }
                abits[0] = (short)f2bf(__builtin_amdgcn_cvt_f32_fp8((int)w0, 0));
                abits[1] = (short)f2bf(__builtin_amdgcn_cvt_f32_fp8((int)w0, 1));
                abits[2] = (short)f2bf(__builtin_amdgcn_cvt_f32_fp8((int)w0, 2));
                abits[3] = (short)f2bf(__builtin_amdgcn_cvt_f32_fp8((int)w0, 3));
                abits[4] = (short)f2bf(__builtin_amdgcn_cvt_f32_fp8((int)w1, 0));
                abits[5] = (short)f2bf(__builtin_amdgcn_cvt_f32_fp8((int)w1, 1));
                abits[6] = (short)f2bf(__builtin_amdgcn_cvt_f32_fp8((int)w1, 2));
                abits[7] = (short)f2bf(__builtin_amdgcn_cvt_f32_fp8((int)w1, 3));
            }
            bf16x8 afrag = __builtin_bit_cast(bf16x8, abits);
            const u16* wp = wpack + ((size_t)(kk * 4) * 64 + lane) * 8;
            #pragma unroll
            for (int nt = 0; nt < 4; ++nt) {
                bf16x8 bfrag = *(const bf16x8*)(wp + (size_t)nt * 64 * 8);
                acc[nt] = __builtin_amdgcn_mfma_f32_16x16x32_bf16(afrag, bfrag, acc[nt], 0, 0, 0);
            }
        }
        #pragma unroll
        for (int reg = 0; reg < 4; ++reg) {
            int r = row0 + kgrp * 4 + reg;
            if (r < n) {
                float dv = dinv[r];
                #pragma unroll
                for (int nt = 0; nt < 4; ++nt)
                    out8[(size_t)r * HID + nt * 16 + r16] = f2fp8(acc[nt][reg] * dv);
            }
        }
    }
}

// ---------- gather helpers ----------
#define CVT4(acc0, acc1, acc2, acc3, wv) \
    acc0 += __builtin_amdgcn_cvt_f32_fp8((int)(wv), 0); \
    acc1 += __builtin_amdgcn_cvt_f32_fp8((int)(wv), 1); \
    acc2 += __builtin_amdgcn_cvt_f32_fp8((int)(wv), 2); \
    acc3 += __builtin_amdgcn_cvt_f32_fp8((int)(wv), 3);

// ---------- CSR gather aggregation, 4 edges/wave (4B per lane), 32-edge unrolled ----------
__global__ __launch_bounds__(256) void agg_csr_kernel(const u8* __restrict__ hp,
                                                      const int* __restrict__ eidx,
                                                      const int* __restrict__ rowend,
                                                      const float* __restrict__ dinv,
                                                      const float* __restrict__ bias,
                                                      u8* __restrict__ out, int n) {
    int w = (blockIdx.x * 256 + threadIdx.x) >> 6;
    int lane = threadIdx.x & 63;
    if (w >= n) return;
    const int g = lane >> 4, fb = lane & 15;
    int beg = (w & (BK - 1)) ? rowend[w - 1] : (w >> SH) * SLOT;
    int end = rowend[w];
    float a0 = 0.f, a1 = 0.f, a2 = 0.f, a3 = 0.f;
    int p = beg;
    for (; p + 32 <= end; p += 32) {
        int s[8];
        #pragma unroll
        for (int j = 0; j < 8; ++j) s[j] = __builtin_nontemporal_load(eidx + p + j * 4 + g);
        u32 wv[8];
        #pragma unroll
        for (int j = 0; j < 8; ++j) wv[j] = *(const u32*)(hp + (size_t)s[j] * 64 + fb * 4);
        #pragma unroll
        for (int j = 0; j < 8; ++j) { CVT4(a0, a1, a2, a3, wv[j]) }
    }
    if (p + 16 <= end) {
        int s[4];
        #pragma unroll
        for (int j = 0; j < 4; ++j) s[j] = __builtin_nontemporal_load(eidx + p + j * 4 + g);
        u32 wv[4];
        #pragma unroll
        for (int j = 0; j < 4; ++j) wv[j] = *(const u32*)(hp + (size_t)s[j] * 64 + fb * 4);
        #pragma unroll
        for (int j = 0; j < 4; ++j) { CVT4(a0, a1, a2, a3, wv[j]) }
        p += 16;
    }
    for (; p < end; p += 4) {
        int idx = p + g;
        bool valid = idx < end;
        int s = __builtin_nontemporal_load(eidx + (valid ? idx : beg));
        u32 wv = *(const u32*)(hp + (size_t)s * 64 + fb * 4);
        if (valid) { CVT4(a0, a1, a2, a3, wv) }
    }
    a0 += __shfl_xor(a0, 16); a0 += __shfl_xor(a0, 32);
    a1 += __shfl_xor(a1, 16); a1 += __shfl_xor(a1, 32);
    a2 += __shfl_xor(a2, 16); a2 += __shfl_xor(a2, 32);
    a3 += __shfl_xor(a3, 16); a3 += __shfl_xor(a3, 32);
    u32 sv = *(const u32*)(hp + (size_t)w * 64 + fb * 4);
    float dv = dinv[w];
    float v0 = fmaxf(dv * (a0 + __builtin_amdgcn_cvt_f32_fp8((int)sv, 0)) + bias[fb * 4 + 0], 0.f);
    float v1 = fmaxf(dv * (a1 + __builtin_amdgcn_cvt_f32_fp8((int)sv, 1)) + bias[fb * 4 + 1], 0.f);
    float v2 = fmaxf(dv * (a2 + __builtin_amdgcn_cvt_f32_fp8((int)sv, 2)) + bias[fb * 4 + 2], 0.f);
    float v3 = fmaxf(dv * (a3 + __builtin_amdgcn_cvt_f32_fp8((int)sv, 3)) + bias[fb * 4 + 3], 0.f);
    if (g == 0) {
        int r = __builtin_amdgcn_cvt_pk_fp8_f32(v0, v1, 0, false);
        r = __builtin_amdgcn_cvt_pk_fp8_f32(v2, v3, r, true);
        *(u32*)(out + (size_t)w * 64 + fb * 4) = (u32)r;
    }
}

// ---------- layer 2: 4-edge/wave CSR aggregation fused with graph-mean partials ----------
__global__ __launch_bounds__(256) void agg_csr_reduce_kernel(const u8* __restrict__ hp,
                                                             const int* __restrict__ eidx,
                                                             const int* __restrict__ rowend,
                                                             const float* __restrict__ dinv,
                                                             const float* __restrict__ bias,
                                                             float* __restrict__ partials, int n) {
    __shared__ float sred[256];
    int t = threadIdx.x, lane = t & 63;
    const int g = lane >> 4, fb = lane & 15;
    int wid = (blockIdx.x * 256 + t) >> 6;
    int wstride = gridDim.x * 4;
    float bl0 = bias[fb * 4 + 0], bl1 = bias[fb * 4 + 1];
    float bl2 = bias[fb * 4 + 2], bl3 = bias[fb * 4 + 3];
    float t0 = 0.f, t1 = 0.f, t2 = 0.f, t3 = 0.f;
    for (int w = wid; w < n; w += wstride) {
        int beg = (w & (BK - 1)) ? rowend[w - 1] : (w >> SH) * SLOT;
        int end = rowend[w];
        float a0 = 0.f, a1 = 0.f, a2 = 0.f, a3 = 0.f;
        int p = beg;
        for (; p + 32 <= end; p += 32) {
            int s[8];
            #pragma unroll
            for (int j = 0; j < 8; ++j) s[j] = __builtin_nontemporal_load(eidx + p + j * 4 + g);
            u32 wv[8];
            #pragma unroll
            for (int j = 0; j < 8; ++j) wv[j] = *(const u32*)(hp + (size_t)s[j] * 64 + fb * 4);
            #pragma unroll
            for (int j = 0; j < 8; ++j) { CVT4(a0, a1, a2, a3, wv[j]) }
        }
        if (p + 16 <= end) {
            int s[4];
            #pragma unroll
            for (int j = 0; j < 4; ++j) s[j] = __builtin_nontemporal_load(eidx + p + j * 4 + g);
            u32 wv[4];
            #pragma unroll
            for (int j = 0; j < 4; ++j) wv[j] = *(const u32*)(hp + (size_t)s[j] * 64 + fb * 4);
            #pragma unroll
            for (int j = 0; j < 4; ++j) { CVT4(a0, a1, a2, a3, wv[j]) }
            p += 16;
        }
        for (; p < end; p += 4) {
            int idx = p + g;
            bool valid = idx < end;
            int s = __builtin_nontemporal_load(eidx + (valid ? idx : beg));
            u32 wv = *(const u32*)(hp + (size_t)s * 64 + fb * 4);
            if (valid) { CVT4(a0, a1, a2, a3, wv) }
        }
        a0 += __shfl_xor(a0, 16); a0 += __shfl_xor(a0, 32);
        a1 += __shfl_xor(a1, 16); a1 += __shfl_xor(a1, 32);
        a2 += __shfl_xor(a2, 16); a2 += __shfl_xor(a2, 32);
        a3 += __shfl_xor(a3, 16); a3 += __shfl_xor(a3, 32);
        u32 sv = *(const u32*)(hp + (size_t)w * 64 + fb * 4);
        float dv = dinv[w];
        t0 += fmaxf(dv * (a0 + __builtin_amdgcn_cvt_f32_fp8((int)sv, 0)) + bl0, 0.f);
        t1 += fmaxf(dv * (a1 + __builtin_amdgcn_cvt_f32_fp8((int)sv, 1)) + bl1, 0.f);
        t2 += fmaxf(dv * (a2 + __builtin_amdgcn_cvt_f32_fp8((int)sv, 2)) + bl2, 0.f);
        t3 += fmaxf(dv * (a3 + __builtin_amdgcn_cvt_f32_fp8((int)sv, 3)) + bl3, 0.f);
    }
    int wv_ = t >> 6;
    if (g == 0) {
        sred[wv_ * 64 + fb * 4 + 0] = t0;
        sred[wv_ * 64 + fb * 4 + 1] = t1;
        sred[wv_ * 64 + fb * 4 + 2] = t2;
        sred[wv_ * 64 + fb * 4 + 3] = t3;
    }
    __syncthreads();
    if (t < 64) partials[blockIdx.x * 64 + t] = sred[t] + sred[t + 64] + sred[t + 128] + sred[t + 192];
}

// ---------- two-stage partial reduction ----------
__global__ __launch_bounds__(256) void gsum_stage_kernel(const float* __restrict__ parts, int nblk,
                                                         float* __restrict__ gsum) {
    __shared__ float sred[256];
    int t = threadIdx.x, col = t & 63;
    float a = 0.f;
    for (int bk = blockIdx.x * 4 + (t >> 6); bk < nblk; bk += gridDim.x * 4)
        a += parts[bk * 64 + col];
    sred[t] = a; __syncthreads();
    if (t < 64) atomicAdd(&gsum[t], sred[t] + sred[t + 64] + sred[t + 128] + sred[t + 192]);
}

__global__ void final_gsum_kernel(const float* __restrict__ gsum, const float* __restrict__ Wf,
                                  const float* __restrict__ bf_, float* __restrict__ out, float invn) {
    int lane = threadIdx.x;
    float v = gsum[lane] * invn * Wf[lane];
    #pragma unroll
    for (int off = 32; off; off >>= 1) v += __shfl_down(v, off);
    if (lane == 0) out[0] = 1.f / (1.f + expf(-(v + bf_[0])));
}

// ================= fallback (atomic aggregation, fp8 hp, VALU gemm) =================
template <int K, typename TIn>
__global__ __launch_bounds__(256) void gemm_scale_kernel(const TIn* __restrict__ A,
                                                         const float* __restrict__ W,
                                                         const float* __restrict__ dinv,
                                                         u8* __restrict__ out8, int n) {
    __shared__ float xs[16][K];
    const int t = threadIdx.x;
    const int row0 = blockIdx.x * 16;
    if constexpr (sizeof(TIn) == 4) {
        const float* Af = (const float*)A;
        for (int i = t; i < 16 * K; i += 256) {
            int r = i / K;
            (&xs[0][0])[i] = (row0 + r < n) ? Af[(size_t)row0 * K + i] : 0.f;
        }
    } else {
        const u8* Ab = (const u8*)A;
        for (int i = t; i < 16 * K; i += 256) {
            int r = i / K;
            (&xs[0][0])[i] = (row0 + r < n) ? fp82f(Ab[(size_t)row0 * K + i]) : 0.f;
        }
    }
    __syncthreads();
    const int c = t & 63, rg = t >> 6;
    float acc[4] = {0.f, 0.f, 0.f, 0.f};
    #pragma unroll 4
    for (int k = 0; k < K; ++k) {
        float w = W[k * HID + c];
        #pragma unroll
        for (int j = 0; j < 4; ++j) acc[j] += xs[rg + 4 * j][k] * w;
    }
    #pragma unroll
    for (int j = 0; j < 4; ++j) {
        int r = row0 + rg + 4 * j;
        if (r < n) out8[(size_t)r * HID + c] = f2fp8(acc[j] * dinv[r]);
    }
}
__global__ void deg_f_kernel(const int* __restrict__ dst, float* __restrict__ deg, int ne) {
    int i = blockIdx.x * blockDim.x + threadIdx.x, st = gridDim.x * blockDim.x;
    for (; i < ne; i += st) atomicAdd(&deg[dst[i]], 1.0f);
}
__global__ void dinvf_kernel(float* __restrict__ deg, int n) {
    int i = blockIdx.x * blockDim.x + threadIdx.x;
    if (i < n) deg[i] = rsqrtf(deg[i] + 1.0f);
}
__global__ __launch_bounds__(256) void aggregate_atomic_kernel(const u8* __restrict__ hp,
        const int* __restrict__ src, const int* __restrict__ dst,
        const float* __restrict__ dinv, float* __restrict__ outf, int ne) {
    size_t tt = (size_t)blockIdx.x * 256 + threadIdx.x;
    int e = (int)(tt >> 6), f = (int)(tt & 63);
    if (e >= ne) return;
    int s = src[e], d = dst[e];
    atomicAdd(&outf[(size_t)d * HID + f], fp82f(hp[s * HID + f]) * dinv[d]);
}
__global__ void finalize1_fb_kernel(u8* __restrict__ hp, const float* __restrict__ agg,
                                    const float* __restrict__ dinv, const float* __restrict__ b, int n) {
    size_t i = (size_t)blockIdx.x * blockDim.x + threadIdx.x;
    if (i >= (size_t)n * HID) return;
    int node = (int)(i >> 6);
    float v = agg[i] + fp82f(hp[i]) * dinv[node] + b[i & 63];
    hp[i] = f2fp8(fmaxf(v, 0.f));
}
__global__ __launch_bounds__(256) void finalize2_fb_kernel(const u8* __restrict__ hp,
        const float* __restrict__ agg, const float* __restrict__ dinv,
        const float* __restrict__ b, float* __restrict__ gsum, int n) {
    __shared__ float sred[256];
    const int t = threadIdx.x, c = t & 63;
    const size_t total = (size_t)n * HID;
    const size_t stride = (size_t)gridDim.x * blockDim.x;
    float acc = 0.f;
    for (size_t i = (size_t)blockIdx.x * blockDim.x + t; i < total; i += stride) {
        int node = (int)(i >> 6);
        acc += fmaxf(agg[i] + fp82f(hp[i]) * dinv[node] + b[c], 0.f);
    }
    sred[t] = acc; __syncthreads();
    if (t < 64) atomicAdd(&gsum[c], sred[t] + sred[t + 64] + sred[t + 128] + sred[t + 192]);
}
__global__ void final_gsum_fb_kernel(const float* __restrict__ gsum, const float* __restrict__ Wf,
                                     const float* __restrict__ bf_, float* __restrict__ out, int n) {
    int lane = threadIdx.x;
    float v = (gsum[lane] / (float)n) * Wf[lane];
    #pragma unroll
    for (int off = 32; off; off >>= 1) v += __shfl_down(v, off);
    if (lane == 0) out[0] = 1.f / (1.f + expf(-(v + bf_[0])));
}

extern "C" void kernel_launch(void* const* d_in, const int* in_sizes, int n_in,
                              void* d_out, int out_size, void* d_ws, size_t ws_size,
                              hipStream_t stream) {
    const float* x  = (const float*)d_in[0];
    const int*   ei = (const int*)d_in[1];
    const float* W1 = (const float*)d_in[2];
    const float* b1 = (const float*)d_in[3];
    const float* W2 = (const float*)d_in[4];
    const float* b2 = (const float*)d_in[5];
    const float* Wf = (const float*)d_in[6];
    const float* bf_ = (const float*)d_in[7];
    float* out = (float*)d_out;

    const int n  = in_sizes[0] / 256;
    const int ne = in_sizes[1] / 2;
    const int* srcp = ei;
    const int* dstp = ei + ne;
    const int B = (n + BK - 1) / BK;

    // ---- primary layout ----
    char* p = (char*)d_ws;
    u32*   ep     = (u32*)p;   p += ((size_t)B * SLOT + 4096) * 4;
    int*   bcur   = (int*)p;   p += BPAD * 4;
    float* dinv   = (float*)p; p += (size_t)n * 4;
    int*   rowend = (int*)p;   p += (size_t)n * 4;
    float* gsum   = (float*)p; p += 64 * 4;
    int*   eidx   = (int*)p;   p += ((size_t)B * SLOT + 4096) * 4;
    float* parts  = (float*)p; p += (size_t)NBLK2 * 64 * 4;
    p = (char*)(((uintptr_t)p + 15) & ~(uintptr_t)15);
    u16*   wpack1 = (u16*)p;   p += 256 * 64 * 2;    // [8][4][64][8]
    u16*   wpack2 = (u16*)p;   p += 64 * 64 * 2;     // [2][4][64][8]
    u8*    hp     = (u8*)p;    p += (size_t)n * HID;
    u8*    h1     = (u8*)p;    p += (size_t)n * HID;
    size_t need = (size_t)(p - (char*)d_ws);

    // average edges per bucket must stay well under SLOT
    bool slack_ok = ((size_t)ne / (size_t)B) <= (size_t)(SLOT - 1024);

    if (ws_size >= need && n <= (1 << 17) && slack_ok) {
        (void)hipMemsetAsync(gsum, 0, 64 * 4, stream);
        init_bcur_kernel<<<(B + 255) / 256, 256, 0, stream>>>(bcur, B);
        partition_kernel<<<(ne + CH - 1) / CH, 256, 0, stream>>>(srcp, dstp, bcur, ep, ne);
        bucket_sort_kernel<<<B, 256, 0, stream>>>(ep, bcur, eidx, rowend, dinv, n);
        pack_w_kernel<256><<<64, 256, 0, stream>>>(W1, wpack1);
        pack_w_kernel<64><<<16, 256, 0, stream>>>(W2, wpack2);

        const int ntiles = (n + 15) / 16;
        const int gblk = (ntiles + 3) / 4;
        mfma_gemm_kernel<256, float><<<gblk, 256, 0, stream>>>(x, wpack1, dinv, hp, n);
        agg_csr_kernel<<<(n + 3) / 4, 256, 0, stream>>>(hp, eidx, rowend, dinv, b1, h1, n);
        mfma_gemm_kernel<64, u8><<<gblk, 256, 0, stream>>>(h1, wpack2, dinv, hp, n);
        agg_csr_reduce_kernel<<<NBLK2, 256, 0, stream>>>(hp, eidx, rowend, dinv, b2, parts, n);
        gsum_stage_kernel<<<128, 256, 0, stream>>>(parts, NBLK2, gsum);
        final_gsum_kernel<<<1, 64, 0, stream>>>(gsum, Wf, bf_, out, 1.0f / (float)n);
    } else {
        // ---- fallback: atomic aggregation, fp8 hp, VALU gemm ----
        char* q = (char*)d_ws;
        float* dinvF = (float*)q; q += (size_t)n * 4;
        float* gsumF = (float*)q; q += 64 * 4;
        u8*    hpF   = (u8*)q;   q += (size_t)n * HID;
        float* aggF  = (float*)q;

        (void)hipMemsetAsync(dinvF, 0, ((size_t)n + 64) * 4, stream);
        deg_f_kernel<<<2048, 256, 0, stream>>>(dstp, dinvF, ne);
        dinvf_kernel<<<(n + 255) / 256, 256, 0, stream>>>(dinvF, n);

        gemm_scale_kernel<256, float><<<(n + 15) / 16, 256, 0, stream>>>(x, W1, dinvF, hpF, n);
        (void)hipMemsetAsync(aggF, 0, (size_t)n * HID * 4, stream);
        aggregate_atomic_kernel<<<(int)(((size_t)ne * 64 + 255) / 256), 256, 0, stream>>>(hpF, srcp, dstp, dinvF, aggF, ne);
        finalize1_fb_kernel<<<(int)(((size_t)n * HID + 255) / 256), 256, 0, stream>>>(hpF, aggF, dinvF, b1, n);

        gemm_scale_kernel<64, u8><<<(n + 15) / 16, 256, 0, stream>>>(hpF, W2, dinvF, hpF, n);
        (void)hipMemsetAsync(aggF, 0, (size_t)n * HID * 4, stream);
        aggregate_atomic_kernel<<<(int)(((size_t)ne * 64 + 255) / 256), 256, 0, stream>>>(hpF, srcp, dstp, dinvF, aggF, ne);
        finalize2_fb_kernel<<<2048, 256, 0, stream>>>(hpF, aggF, dinvF, b2, gsumF, n);
        final_gsum_fb_kernel<<<1, 64, 0, stream>>>(gsumF, Wf, bf_, out, n);
    }
}